// Round 6
// baseline (288.539 us; speedup 1.0000x reference)
//
#include <hip/hip_runtime.h>
#include <math.h>

typedef __attribute__((ext_vector_type(8))) short short8;
typedef __attribute__((ext_vector_type(4))) float floatx4;
typedef __attribute__((ext_vector_type(2))) unsigned uint2v;

__device__ __forceinline__ float sig(float z) { return 1.0f / (1.0f + __expf(-z)); }

__device__ __forceinline__ unsigned short f2bf(float f) {
    unsigned u = __float_as_uint(f);
    u = (u + 0x7FFFu + ((u >> 16) & 1u)) >> 16;   // RNE
    return (unsigned short)u;
}

// v_cvt_pk_bf16_f32: packs 2 f32 -> 2 bf16 (RNE) in one instruction.
__device__ __forceinline__ unsigned cvtpk_bf16(float lo, float hi) {
    unsigned r;
    asm("v_cvt_pk_bf16_f32 %0, %1, %2" : "=v"(r) : "v"(lo), "v"(hi));
    return r;
}

// 4 floats -> 4 bf16 (8B store), RNE identical to f2bf.
__device__ __forceinline__ void st_pack4(unsigned short* p, float v0, float v1, float v2, float v3) {
    uint2v u;
    u.x = cvtpk_bf16(v0, v1);
    u.y = cvtpk_bf16(v2, v3);
    *(uint2v*)p = u;
}

// All four W1 matrices -> bf16 pre-swizzled MFMA 16x16x32 B-frag order.
// blk = (n>>4)*(H/32) + (k>>5), lane = ((k>>3)&3)*16 + (n&15), j = k&7.
__global__ void convert_all(const float* __restrict__ s0, const float* __restrict__ s1,
                            const float* __restrict__ s2, const float* __restrict__ s3,
                            unsigned short* __restrict__ ws) {
    int idx = blockIdx.x * 256 + threadIdx.x;          // 0 .. 458751
    const float* src; unsigned short* dst; int H, logH, local;
    if (idx < 262144) { src = s0; dst = ws; H = 512; logH = 9; local = idx; }
    else {
        int r = idx - 262144; int m = r >> 16; local = r & 65535;
        H = 256; logH = 8;
        src = (m == 0) ? s1 : (m == 1) ? s2 : s3;
        dst = ws + 262144 + m * 65536;
    }
    int n = local & (H - 1), k = local >> logH;
    int KT = H >> 5;
    int blk = (n >> 4) * KT + (k >> 5);
    int lane = ((k >> 3) & 3) * 16 + (n & 15);
    int j = k & 7;
    dst[(blk * 64 + lane) * 8 + j] = f2bf(src[local]);
}

// R6 (on R5's 208us base; R5 audit: L0 A-tile stores were 4-way bank-conflicted
// because slot=(kq*16+row)^sw leaves bank independent of kq (kq*64 = 0 mod 32
// banks) -> the 4 kq groups collide in every b64-store phase, ~0.8e7 of the
// 1.25e7 conflict cycles):
//  - kq folded into bank bits: store slot ^= (kq<<1); read lane ^= (quad<<1)
//    (same involution both sides -> bit-identical values, conflict-free phases).
//  - T14 issue-early: cp0's b0 fragment loads hoisted above the L0 phase
//    (+16 live VGPR only; 170-reg budget holds, no spill).
struct PosS {
    float B0[512], B1[512], W2[1536];
    float Q[4][8], Qd[4][8];
    float Sum[32][3];
};
struct RpyS {
    float B0[256], B1[256], W2[512];
    float Q[8][8], Qd[8][8];
    float Sum[64][2];
};

__global__ __launch_bounds__(256, 3)
void fused_mfma(const float* __restrict__ x,
                const float* __restrict__ pW0, const float* __restrict__ pb0,
                const float* __restrict__ pb1,
                const float* __restrict__ pW2, const float* __restrict__ pb2,
                const float* __restrict__ rW0_, const float* __restrict__ rb0_,
                const float* __restrict__ rb1_,
                const float* __restrict__ rW2_, const float* __restrict__ rb2_,
                const float* __restrict__ piW0, const float* __restrict__ pib0,
                const float* __restrict__ pib1,
                const float* __restrict__ piW2, const float* __restrict__ pib2,
                const float* __restrict__ yW0, const float* __restrict__ yb0,
                const float* __restrict__ yb1,
                const float* __restrict__ yW2, const float* __restrict__ yb2,
                const unsigned short* __restrict__ wsBase,
                float* __restrict__ out, int ns)
{
    extern __shared__ unsigned short sA[];      // 34816B: A-tile (16KB) then f32 partials
    __shared__ union { PosS p; RpyS r; } sU;

    const int tid = threadIdx.x;
    const int xcd  = blockIdx.x & 7;
    const int slot = blockIdx.x >> 3;           // 0..1279 within this XCD
    const int o_l  = slot / 5, r5 = slot % 5;
    const int o = xcd + (o_l << 3);             // sample-octet 0..2047

    const size_t JTOT = (size_t)ns * 18, OUTA = (size_t)ns * 81, JANG = (size_t)ns * 87;
    const floatx4 z4 = {0.f, 0.f, 0.f, 0.f};
    const int w = tid >> 6, lane = tid & 63;
    const int quad = lane >> 4, col = lane & 15;
    const int srcl = lane & 47;
    const int lxk = lane ^ (quad << 1);         // kq-swizzled read index

    if (r5 < 2) {
        // ============ POS: 7 -> 512 -> 512 -> 3, 4 samples (32 rows) ============
        const int m0 = (o * 2 + r5) * 4;
        const unsigned short* wsW1 = wsBase;

        for (int i = tid; i < 512;  i += 256) { sU.p.B0[i] = pb0[i]; sU.p.B1[i] = pb1[i]; }
        for (int i = tid; i < 1536; i += 256) sU.p.W2[i] = pW2[i];
        if (tid < 56) {
            int m = tid / 14, c = tid % 14;
            float v = x[(m0 + m) * 14 + c];
            if (c < 7) sU.p.Q[m][c] = v; else sU.p.Qd[m][c - 7] = v;
        }
        __syncthreads();

        const float4* W04 = (const float4*)pW0;

        floatx4 acc[2][8];
        #pragma unroll
        for (int rt = 0; rt < 2; rt++)
            #pragma unroll
            for (int ct = 0; ct < 8; ct++) acc[rt][ct] = z4;

        const short8* bbase = (const short8*)wsW1 + (size_t)(w * 8 * 16) * 64 + lane;
        short8 b0[4], b1[4], b2[4];

#define PLD(B, KT) { \
            B[0] = bbase[((cp4 + 0) * 16 + hh8 + (KT)) * 64]; \
            B[1] = bbase[((cp4 + 1) * 16 + hh8 + (KT)) * 64]; \
            B[2] = bbase[((cp4 + 2) * 16 + hh8 + (KT)) * 64]; \
            B[3] = bbase[((cp4 + 3) * 16 + hh8 + (KT)) * 64]; }
#define PST(B, KT) { \
            const short8 a0 = *(const short8*)&sA[(0 * 8 + (KT)) * 512 + (lxk ^ (KT)) * 8]; \
            const short8 a1 = *(const short8*)&sA[(1 * 8 + (KT)) * 512 + (lxk ^ (KT)) * 8]; \
            acc[0][cp4 + 0] = __builtin_amdgcn_mfma_f32_16x16x32_bf16(a0, B[0], acc[0][cp4 + 0], 0, 0, 0); \
            acc[1][cp4 + 0] = __builtin_amdgcn_mfma_f32_16x16x32_bf16(a1, B[0], acc[1][cp4 + 0], 0, 0, 0); \
            acc[0][cp4 + 1] = __builtin_amdgcn_mfma_f32_16x16x32_bf16(a0, B[1], acc[0][cp4 + 1], 0, 0, 0); \
            acc[1][cp4 + 1] = __builtin_amdgcn_mfma_f32_16x16x32_bf16(a1, B[1], acc[1][cp4 + 1], 0, 0, 0); \
            acc[0][cp4 + 2] = __builtin_amdgcn_mfma_f32_16x16x32_bf16(a0, B[2], acc[0][cp4 + 2], 0, 0, 0); \
            acc[1][cp4 + 2] = __builtin_amdgcn_mfma_f32_16x16x32_bf16(a1, B[2], acc[1][cp4 + 2], 0, 0, 0); \
            acc[0][cp4 + 3] = __builtin_amdgcn_mfma_f32_16x16x32_bf16(a0, B[3], acc[0][cp4 + 3], 0, 0, 0); \
            acc[1][cp4 + 3] = __builtin_amdgcn_mfma_f32_16x16x32_bf16(a1, B[3], acc[1][cp4 + 3], 0, 0, 0); }

        #pragma unroll
        for (int hh = 0; hh < 2; ++hh) {
            const int hh8 = hh * 8;
            // T14: cp0's first fragment set, issued before L0 (independent of sA)
            b0[0] = bbase[(0 * 16 + hh8) * 64];
            b0[1] = bbase[(1 * 16 + hh8) * 64];
            b0[2] = bbase[(2 * 16 + hh8) * 64];
            b0[3] = bbase[(3 * 16 + hh8) * 64];
            // ---- layer 0, K-half hh: 256 threads = 4 samples x 32 k8 x 2 jj-halves ----
            {
                const int jh = tid & 1, item = tid >> 1;
                const int s = item >> 5, k8l = item & 31, k8 = (hh << 5) | k8l;
                float q[7], w0v[7][4];
                #pragma unroll
                for (int i = 0; i < 7; i++) {
                    q[i] = sU.p.Q[s][i];
                    float4 a = W04[i * 128 + k8 * 2 + jh];
                    w0v[i][0] = a.x; w0v[i][1] = a.y; w0v[i][2] = a.z; w0v[i][3] = a.w;
                }
                float hv[4], dv[4];
                #pragma unroll
                for (int jj = 0; jj < 4; jj++) {
                    float z = sU.p.B0[k8 * 8 + jh * 4 + jj];
                    #pragma unroll
                    for (int i = 0; i < 7; i++) z = fmaf(q[i], w0v[i][jj], z);
                    float h = sig(z);
                    hv[jj] = h; dv[jj] = h - h * h;
                }
                const int ktl = k8l >> 2, kq = k8l & 3;
                const int kxr = (kq << 4) ^ (kq << 1) ^ ktl;   // slot = kxr ^ (rr&15)
                const int rr0 = s * 8;
                st_pack4(&sA[((rr0 >> 4) * 8 + ktl) * 512 + (kxr ^ (rr0 & 15)) * 8 + jh * 4],
                         hv[0], hv[1], hv[2], hv[3]);
                #pragma unroll
                for (int i = 0; i < 7; i++) {
                    const int rr = rr0 + 1 + i;
                    st_pack4(&sA[((rr >> 4) * 8 + ktl) * 512 + (kxr ^ (rr & 15)) * 8 + jh * 4],
                             dv[0] * w0v[i][0], dv[1] * w0v[i][1], dv[2] * w0v[i][2], dv[3] * w0v[i][3]);
                }
            }
            __syncthreads();

            // ---- layer 1 MFMA over this K-half, 2 ct-passes of 4, 3-buf rotation ----
            #pragma unroll
            for (int cp = 0; cp < 2; ++cp) {
                const int cp4 = cp * 4;
                if (cp) PLD(b0, 0);
                PLD(b1, 1); PLD(b2, 2);
                __builtin_amdgcn_s_setprio(1);
                PST(b0, 0); PLD(b0, 3);
                PST(b1, 1); PLD(b1, 4);
                PST(b2, 2); PLD(b2, 5);
                PST(b0, 3); PLD(b0, 6);
                PST(b1, 4); PLD(b1, 7);
                PST(b2, 5);
                PST(b0, 6);
                PST(b1, 7);
                __builtin_amdgcn_s_setprio(0);
            }
            if (hh == 0) __syncthreads();   // drain reads before half-1 overwrites sA
        }
#undef PLD
#undef PST

        float ep[2][4][3];
        #pragma unroll
        for (int a = 0; a < 2; a++) for (int b = 0; b < 4; b++) for (int c = 0; c < 3; c++) ep[a][b][c] = 0.f;

        #pragma unroll
        for (int ct = 0; ct < 8; ++ct) {
            const int n = w * 128 + ct * 16 + col;
            const float b1n = sU.p.B1[n];
            const float w20 = sU.p.W2[n * 3], w21 = sU.p.W2[n * 3 + 1], w22 = sU.p.W2[n * 3 + 2];
            #pragma unroll
            for (int rt = 0; rt < 2; ++rt) {
                float z2c = __shfl(acc[rt][ct][0], srcl);
                float h2 = sig(z2c + b1n);
                float d2 = h2 - h2 * h2;
                #pragma unroll
                for (int r = 0; r < 4; ++r) {
                    float gg = ((quad & 1) == 0 && r == 0) ? h2 : d2 * acc[rt][ct][r];
                    ep[rt][r][0] = fmaf(gg, w20, ep[rt][r][0]);
                    ep[rt][r][1] = fmaf(gg, w21, ep[rt][r][1]);
                    ep[rt][r][2] = fmaf(gg, w22, ep[rt][r][2]);
                }
            }
        }

        // LDS-transpose reduce: partials [w][row][j][17] f32 in sA
        __syncthreads();                        // all waves done reading A-tile
        {
            float* pl = (float*)sA;
            #pragma unroll
            for (int rt = 0; rt < 2; ++rt)
                #pragma unroll
                for (int r = 0; r < 4; ++r) {
                    int row = rt * 16 + quad * 4 + r;
                    int base = ((w * 32 + row) * 3) * 17 + col;
                    pl[base]      = ep[rt][r][0];
                    pl[base + 17] = ep[rt][r][1];
                    pl[base + 34] = ep[rt][r][2];
                }
        }
        __syncthreads();

        if (tid < 96) {
            const float* pl = (const float*)sA;
            int row = tid / 3, j = tid % 3;
            float v = 0.f;
            #pragma unroll
            for (int ww = 0; ww < 4; ++ww) {
                const float* q = &pl[((ww * 32 + row) * 3 + j) * 17];
                #pragma unroll
                for (int c = 0; c < 16; ++c) v += q[c];
            }
            int s = row >> 3, i = row & 7;
            size_t M = m0 + s;
            if (i == 0) { v += pb2[j]; out[M * 18 + j] = v; out[OUTA + M * 6 + j] = v; }
            else        { out[JTOT + M * 63 + j * 7 + (i - 1)] = v;
                          out[JANG + M * 42 + j * 7 + (i - 1)] = v; }
            sU.p.Sum[row][j] = v;
        }
        __syncthreads();
        if (tid < 12) {
            int s = tid / 3, j = tid % 3;
            float vel = 0.f;
            #pragma unroll
            for (int i = 0; i < 7; i++) vel = fmaf(sU.p.Sum[s * 8 + 1 + i][j], sU.p.Qd[s][i], vel);
            out[(size_t)(m0 + s) * 18 + 9 + j] = vel;
        }
    } else {
        // ============ RPY: 7 -> 256 -> 256 -> 2, 8 samples (64 rows) ============
        const int h = r5 - 2;
        const int m0 = o * 8;
        const float* W0 = (h == 0) ? rW0_ : (h == 1) ? piW0 : yW0;
        const float* b0p = (h == 0) ? rb0_ : (h == 1) ? pib0 : yb0;
        const float* b1p = (h == 0) ? rb1_ : (h == 1) ? pib1 : yb1;
        const float* W2 = (h == 0) ? rW2_ : (h == 1) ? piW2 : yW2;
        const float* b2p = (h == 0) ? rb2_ : (h == 1) ? pib2 : yb2;
        const unsigned short* wsW1 = wsBase + 262144 + h * 65536;

        if (tid < 256) { sU.r.B0[tid] = b0p[tid]; sU.r.B1[tid] = b1p[tid]; }
        for (int i = tid; i < 512; i += 256) sU.r.W2[i] = W2[i];
        if (tid < 112) {
            int m = tid / 14, c = tid % 14;
            float v = x[(m0 + m) * 14 + c];
            if (c < 7) sU.r.Q[m][c] = v; else sU.r.Qd[m][c - 7] = v;
        }
        __syncthreads();

        const float4* W04 = (const float4*)W0;

        floatx4 acc[4][4];
        #pragma unroll
        for (int rt = 0; rt < 4; rt++)
            #pragma unroll
            for (int ct = 0; ct < 4; ct++) acc[rt][ct] = z4;

        const short8* bbase = (const short8*)wsW1 + (size_t)(w * 4 * 8) * 64 + lane;
        short8 b0[2], b1[2], b2[2];

#define RLD(B, KT) { \
            B[0] = bbase[((cp2 + 0) * 8 + hh4 + (KT)) * 64]; \
            B[1] = bbase[((cp2 + 1) * 8 + hh4 + (KT)) * 64]; }
#define RST(B, KT) { \
            const int sw_ = hh4 + (KT); \
            const short8 a0 = *(const short8*)&sA[(0 * 4 + (KT)) * 512 + (lxk ^ sw_) * 8]; \
            const short8 a1 = *(const short8*)&sA[(1 * 4 + (KT)) * 512 + (lxk ^ sw_) * 8]; \
            const short8 a2 = *(const short8*)&sA[(2 * 4 + (KT)) * 512 + (lxk ^ sw_) * 8]; \
            const short8 a3 = *(const short8*)&sA[(3 * 4 + (KT)) * 512 + (lxk ^ sw_) * 8]; \
            acc[0][cp2 + 0] = __builtin_amdgcn_mfma_f32_16x16x32_bf16(a0, B[0], acc[0][cp2 + 0], 0, 0, 0); \
            acc[1][cp2 + 0] = __builtin_amdgcn_mfma_f32_16x16x32_bf16(a1, B[0], acc[1][cp2 + 0], 0, 0, 0); \
            acc[2][cp2 + 0] = __builtin_amdgcn_mfma_f32_16x16x32_bf16(a2, B[0], acc[2][cp2 + 0], 0, 0, 0); \
            acc[3][cp2 + 0] = __builtin_amdgcn_mfma_f32_16x16x32_bf16(a3, B[0], acc[3][cp2 + 0], 0, 0, 0); \
            acc[0][cp2 + 1] = __builtin_amdgcn_mfma_f32_16x16x32_bf16(a0, B[1], acc[0][cp2 + 1], 0, 0, 0); \
            acc[1][cp2 + 1] = __builtin_amdgcn_mfma_f32_16x16x32_bf16(a1, B[1], acc[1][cp2 + 1], 0, 0, 0); \
            acc[2][cp2 + 1] = __builtin_amdgcn_mfma_f32_16x16x32_bf16(a2, B[1], acc[2][cp2 + 1], 0, 0, 0); \
            acc[3][cp2 + 1] = __builtin_amdgcn_mfma_f32_16x16x32_bf16(a3, B[1], acc[3][cp2 + 1], 0, 0, 0); }

        #pragma unroll
        for (int hh = 0; hh < 2; ++hh) {
            const int hh4 = hh * 4;
            // T14: cp0's first fragment set, issued before L0 (independent of sA)
            b0[0] = bbase[(0 * 8 + hh4) * 64];
            b0[1] = bbase[(1 * 8 + hh4) * 64];
            // ---- layer 0, K-half hh: 256 threads = 8 samples x 16 k8 x 2 jj-halves ----
            {
                const int jh = tid & 1, item = tid >> 1;
                const int s = item >> 4, k8l = item & 15, k8 = (hh << 4) | k8l;
                float q[7], w0v[7][4];
                #pragma unroll
                for (int i = 0; i < 7; i++) {
                    q[i] = sU.r.Q[s][i];
                    float4 a = W04[i * 64 + k8 * 2 + jh];
                    w0v[i][0] = a.x; w0v[i][1] = a.y; w0v[i][2] = a.z; w0v[i][3] = a.w;
                }
                float hv[4], dv[4];
                #pragma unroll
                for (int jj = 0; jj < 4; jj++) {
                    float z = sU.r.B0[k8 * 8 + jh * 4 + jj];
                    #pragma unroll
                    for (int i = 0; i < 7; i++) z = fmaf(q[i], w0v[i][jj], z);
                    float hhh = sig(z);
                    hv[jj] = hhh; dv[jj] = hhh - hhh * hhh;
                }
                const int ktl = k8l >> 2, kq = k8l & 3;
                const int sw = (hh << 2) | ktl;              // global kt & 7
                const int kxr = (kq << 4) ^ (kq << 1) ^ sw;  // slot = kxr ^ (rr&15)
                const int rr0 = s * 8;
                st_pack4(&sA[((rr0 >> 4) * 4 + ktl) * 512 + (kxr ^ (rr0 & 15)) * 8 + jh * 4],
                         hv[0], hv[1], hv[2], hv[3]);
                #pragma unroll
                for (int i = 0; i < 7; i++) {
                    const int rr = rr0 + 1 + i;
                    st_pack4(&sA[((rr >> 4) * 4 + ktl) * 512 + (kxr ^ (rr & 15)) * 8 + jh * 4],
                             dv[0] * w0v[i][0], dv[1] * w0v[i][1], dv[2] * w0v[i][2], dv[3] * w0v[i][3]);
                }
            }
            __syncthreads();

            // ---- layer 1 MFMA over this K-half, 2 ct-passes of 2, 3-buf rotation ----
            #pragma unroll
            for (int cp = 0; cp < 2; ++cp) {
                const int cp2 = cp * 2;
                if (cp) RLD(b0, 0);
                RLD(b1, 1); RLD(b2, 2);
                __builtin_amdgcn_s_setprio(1);
                RST(b0, 0); RLD(b0, 3);
                RST(b1, 1);
                RST(b2, 2);
                RST(b0, 3);
                __builtin_amdgcn_s_setprio(0);
            }
            if (hh == 0) __syncthreads();   // drain reads before half-1 overwrites sA
        }
#undef RLD
#undef RST

        float ep[4][4][2];
        #pragma unroll
        for (int a = 0; a < 4; a++) for (int b = 0; b < 4; b++) for (int c = 0; c < 2; c++) ep[a][b][c] = 0.f;

        #pragma unroll
        for (int ct = 0; ct < 4; ++ct) {
            const int n = w * 64 + ct * 16 + col;
            const float b1n = sU.r.B1[n];
            const float w20 = sU.r.W2[n * 2], w21 = sU.r.W2[n * 2 + 1];
            #pragma unroll
            for (int rt = 0; rt < 4; ++rt) {
                float z2c = __shfl(acc[rt][ct][0], srcl);
                float h2 = sig(z2c + b1n);
                float d2 = h2 - h2 * h2;
                #pragma unroll
                for (int r = 0; r < 4; ++r) {
                    float gg = ((quad & 1) == 0 && r == 0) ? h2 : d2 * acc[rt][ct][r];
                    ep[rt][r][0] = fmaf(gg, w20, ep[rt][r][0]);
                    ep[rt][r][1] = fmaf(gg, w21, ep[rt][r][1]);
                }
            }
        }

        // LDS-transpose reduce: partials [w][row][j][17] f32 in sA
        __syncthreads();                        // all waves done reading A-tile
        {
            float* pl = (float*)sA;
            #pragma unroll
            for (int rt = 0; rt < 4; ++rt)
                #pragma unroll
                for (int r = 0; r < 4; ++r) {
                    int row = rt * 16 + quad * 4 + r;
                    int base = ((w * 64 + row) * 2) * 17 + col;
                    pl[base]      = ep[rt][r][0];
                    pl[base + 17] = ep[rt][r][1];
                }
        }
        __syncthreads();

        if (tid < 128) {
            const float* pl = (const float*)sA;
            int row = tid >> 1, j = tid & 1;
            float v = 0.f;
            #pragma unroll
            for (int ww = 0; ww < 4; ++ww) {
                const float* q = &pl[((ww * 64 + row) * 2 + j) * 17];
                #pragma unroll
                for (int c = 0; c < 16; ++c) v += q[c];
            }
            if ((row & 7) == 0) v += b2p[j];
            sU.r.Sum[row][j] = v;
        }
        __syncthreads();

        if (tid < 8) {
            int s = tid;
            size_t M = m0 + s;
            float y0 = sU.r.Sum[s * 8][0], y1 = sU.r.Sum[s * 8][1];
            float sv = sinf(y0), cv = cosf(y1);
            out[M * 18 + 3 + h] = sv;
            out[M * 18 + 6 + h] = cv;
            out[OUTA + M * 6 + 3 + h] = atan2f(sv, cv);
            float f0 = cosf(y0), f1 = -sinf(y1);
            float inv = 1.0f / fmaf(sv, sv, cv * cv);
            float v0 = 0.f, v1 = 0.f;
            #pragma unroll
            for (int i = 0; i < 7; i++) {
                float r0 = f0 * sU.r.Sum[s * 8 + 1 + i][0];
                float r1 = f1 * sU.r.Sum[s * 8 + 1 + i][1];
                out[JTOT + M * 63 + (3 + h) * 7 + i] = r0;
                out[JTOT + M * 63 + (6 + h) * 7 + i] = r1;
                out[JANG + M * 42 + (3 + h) * 7 + i] = (cv * r0 - sv * r1) * inv;
                v0 = fmaf(r0, sU.r.Qd[s][i], v0);
                v1 = fmaf(r1, sU.r.Qd[s][i], v1);
            }
            out[M * 18 + 12 + h] = v0;
            out[M * 18 + 15 + h] = v1;
        }
    }
}

extern "C" void kernel_launch(void* const* d_in, const int* in_sizes, int n_in,
                              void* d_out, int out_size, void* d_ws, size_t ws_size,
                              hipStream_t stream) {
    (void)n_in; (void)out_size; (void)ws_size;
    const float* x = (const float*)d_in[0];
    float* out = (float*)d_out;
    unsigned short* ws = (unsigned short*)d_ws;
    const int ns = in_sizes[0] / 14;

    convert_all<<<dim3(1792), 256, 0, stream>>>(
        (const float*)d_in[3], (const float*)d_in[9],
        (const float*)d_in[15], (const float*)d_in[21], ws);

    // 10240 blocks (2048 octets x 5 roles); 34816B dynamic LDS
    fused_mfma<<<dim3((ns / 8) * 5), 256, 34816, stream>>>(
        x,
        (const float*)d_in[1],  (const float*)d_in[2],  (const float*)d_in[4],
        (const float*)d_in[5],  (const float*)d_in[6],
        (const float*)d_in[7],  (const float*)d_in[8],  (const float*)d_in[10],
        (const float*)d_in[11], (const float*)d_in[12],
        (const float*)d_in[13], (const float*)d_in[14], (const float*)d_in[16],
        (const float*)d_in[17], (const float*)d_in[18],
        (const float*)d_in[19], (const float*)d_in[20], (const float*)d_in[22],
        (const float*)d_in[23], (const float*)d_in[24],
        ws, out, ns);
}

// Round 7
// 286.886 us; speedup vs baseline: 1.0058x; 1.0058x over previous
//
#include <hip/hip_runtime.h>
#include <math.h>

typedef __attribute__((ext_vector_type(8))) short short8;
typedef __attribute__((ext_vector_type(4))) float floatx4;
typedef __attribute__((ext_vector_type(2))) unsigned uint2v;

__device__ __forceinline__ float sig(float z) { return 1.0f / (1.0f + __expf(-z)); }

__device__ __forceinline__ unsigned short f2bf(float f) {
    unsigned u = __float_as_uint(f);
    u = (u + 0x7FFFu + ((u >> 16) & 1u)) >> 16;   // RNE
    return (unsigned short)u;
}

// v_cvt_pk_bf16_f32: packs 2 f32 -> 2 bf16 (RNE) in one instruction.
__device__ __forceinline__ unsigned cvtpk_bf16(float lo, float hi) {
    unsigned r;
    asm("v_cvt_pk_bf16_f32 %0, %1, %2" : "=v"(r) : "v"(lo), "v"(hi));
    return r;
}

// 4 floats -> 4 bf16 (8B store), RNE identical to f2bf.
__device__ __forceinline__ void st_pack4(unsigned short* p, float v0, float v1, float v2, float v3) {
    uint2v u;
    u.x = cvtpk_bf16(v0, v1);
    u.y = cvtpk_bf16(v2, v3);
    *(uint2v*)p = u;
}

// All four W1 matrices -> bf16 pre-swizzled MFMA 16x16x32 B-frag order.
// blk = (n>>4)*(H/32) + (k>>5), lane = ((k>>3)&3)*16 + (n&15), j = k&7.
__global__ void convert_all(const float* __restrict__ s0, const float* __restrict__ s1,
                            const float* __restrict__ s2, const float* __restrict__ s3,
                            unsigned short* __restrict__ ws) {
    int idx = blockIdx.x * 256 + threadIdx.x;          // 0 .. 458751
    const float* src; unsigned short* dst; int H, logH, local;
    if (idx < 262144) { src = s0; dst = ws; H = 512; logH = 9; local = idx; }
    else {
        int r = idx - 262144; int m = r >> 16; local = r & 65535;
        H = 256; logH = 8;
        src = (m == 0) ? s1 : (m == 1) ? s2 : s3;
        dst = ws + 262144 + m * 65536;
    }
    int n = local & (H - 1), k = local >> logH;
    int KT = H >> 5;
    int blk = (n >> 4) * KT + (k >> 5);
    int lane = ((k >> 3) & 3) * 16 + (n & 15);
    int j = k & 7;
    dst[(blk * 64 + lane) * 8 + j] = f2bf(src[local]);
}

// R7 (on R6's 203.8us base; R6 post-mortem: conflicts -63% but dur -2% ->
// dead time is phase-transition latency, not LDS. MFMA floor ~54us, VALU
// ~95us, dur 203 -> 2x above the overlap floor):
//  - K-halves MERGED back into one full-K L0 phase + one contiguous MFMA
//    phase (the R3 split existed for LDS occupancy; the 34816B partials
//    buffer already fits the full 32KB A-tile). Removes 2 barriers and a
//    full pipeline drain/refill per block; 3-buf rotation runs 16 deep.
//  - T14: B1/W2 held in regs from block start (pos 8, rpy 3 regs), written
//    to LDS after MFMA, covered by the ep barrier. First barrier now waits
//    only on B0+Q (~550 floats, was ~2600).
//  - Barriers/block 7 -> 5. Numerics bit-identical to R6.
// Sentinels: FETCH ~4.5MB (spill), VGPR <= ~120.
struct PosS {
    float B0[512], B1[512], W2[1536];
    float Q[4][8], Qd[4][8];
    float Sum[32][3];
};
struct RpyS {
    float B0[256], B1[256], W2[512];
    float Q[8][8], Qd[8][8];
    float Sum[64][2];
};

__global__ __launch_bounds__(256, 3)
void fused_mfma(const float* __restrict__ x,
                const float* __restrict__ pW0, const float* __restrict__ pb0,
                const float* __restrict__ pb1,
                const float* __restrict__ pW2, const float* __restrict__ pb2,
                const float* __restrict__ rW0_, const float* __restrict__ rb0_,
                const float* __restrict__ rb1_,
                const float* __restrict__ rW2_, const float* __restrict__ rb2_,
                const float* __restrict__ piW0, const float* __restrict__ pib0,
                const float* __restrict__ pib1,
                const float* __restrict__ piW2, const float* __restrict__ pib2,
                const float* __restrict__ yW0, const float* __restrict__ yb0,
                const float* __restrict__ yb1,
                const float* __restrict__ yW2, const float* __restrict__ yb2,
                const unsigned short* __restrict__ wsBase,
                float* __restrict__ out, int ns)
{
    extern __shared__ unsigned short sA[];      // 34816B: 32KB A-tile, then f32 partials
    __shared__ union { PosS p; RpyS r; } sU;

    const int tid = threadIdx.x;
    const int xcd  = blockIdx.x & 7;
    const int slot = blockIdx.x >> 3;           // 0..1279 within this XCD
    const int o_l  = slot / 5, r5 = slot % 5;
    const int o = xcd + (o_l << 3);             // sample-octet 0..2047

    const size_t JTOT = (size_t)ns * 18, OUTA = (size_t)ns * 81, JANG = (size_t)ns * 87;
    const floatx4 z4 = {0.f, 0.f, 0.f, 0.f};
    const int w = tid >> 6, lane = tid & 63;
    const int quad = lane >> 4, col = lane & 15;
    const int srcl = lane & 47;
    const int lxk = lane ^ (quad << 1);         // kq-swizzled read index

    if (r5 < 2) {
        // ============ POS: 7 -> 512 -> 512 -> 3, 4 samples (32 rows) ============
        const int m0 = (o * 2 + r5) * 4;
        const unsigned short* wsW1 = wsBase;

        // T14: epilogue params straight into regs (consumed post-MFMA)
        const float b1r0 = pb1[tid], b1r1 = pb1[tid + 256];
        float w2r[6];
        #pragma unroll
        for (int t = 0; t < 6; ++t) w2r[t] = pW2[tid + 256 * t];

        for (int i = tid; i < 512; i += 256) sU.p.B0[i] = pb0[i];
        if (tid < 56) {
            int m = tid / 14, c = tid % 14;
            float v = x[(m0 + m) * 14 + c];
            if (c < 7) sU.p.Q[m][c] = v; else sU.p.Qd[m][c - 7] = v;
        }
        __syncthreads();

        const float4* W04 = (const float4*)pW0;

        floatx4 acc[2][8];
        #pragma unroll
        for (int rt = 0; rt < 2; rt++)
            #pragma unroll
            for (int ct = 0; ct < 8; ct++) acc[rt][ct] = z4;

        const short8* bbase = (const short8*)wsW1 + (size_t)(w * 8 * 16) * 64 + lane;
        short8 b0[4], b1[4], b2[4];

#define PLD(B, KT) { \
            B[0] = bbase[((cp4 + 0) * 16 + (KT)) * 64]; \
            B[1] = bbase[((cp4 + 1) * 16 + (KT)) * 64]; \
            B[2] = bbase[((cp4 + 2) * 16 + (KT)) * 64]; \
            B[3] = bbase[((cp4 + 3) * 16 + (KT)) * 64]; }
#define PST(B, KT) { \
            const int sw_ = (KT) & 7; \
            const short8 a0 = *(const short8*)&sA[(0 * 16 + (KT)) * 512 + (lxk ^ sw_) * 8]; \
            const short8 a1 = *(const short8*)&sA[(1 * 16 + (KT)) * 512 + (lxk ^ sw_) * 8]; \
            acc[0][cp4 + 0] = __builtin_amdgcn_mfma_f32_16x16x32_bf16(a0, B[0], acc[0][cp4 + 0], 0, 0, 0); \
            acc[1][cp4 + 0] = __builtin_amdgcn_mfma_f32_16x16x32_bf16(a1, B[0], acc[1][cp4 + 0], 0, 0, 0); \
            acc[0][cp4 + 1] = __builtin_amdgcn_mfma_f32_16x16x32_bf16(a0, B[1], acc[0][cp4 + 1], 0, 0, 0); \
            acc[1][cp4 + 1] = __builtin_amdgcn_mfma_f32_16x16x32_bf16(a1, B[1], acc[1][cp4 + 1], 0, 0, 0); \
            acc[0][cp4 + 2] = __builtin_amdgcn_mfma_f32_16x16x32_bf16(a0, B[2], acc[0][cp4 + 2], 0, 0, 0); \
            acc[1][cp4 + 2] = __builtin_amdgcn_mfma_f32_16x16x32_bf16(a1, B[2], acc[1][cp4 + 2], 0, 0, 0); \
            acc[0][cp4 + 3] = __builtin_amdgcn_mfma_f32_16x16x32_bf16(a0, B[3], acc[0][cp4 + 3], 0, 0, 0); \
            acc[1][cp4 + 3] = __builtin_amdgcn_mfma_f32_16x16x32_bf16(a1, B[3], acc[1][cp4 + 3], 0, 0, 0); }

        {
            // T14: cp0's first fragment set, issued before L0 (independent of sA)
            const int cp4 = 0;
            PLD(b0, 0);
        }

        // ---- layer 0, full K: 512 items (4 samples x 64 k8 x 2 jj-halves) ----
        #pragma unroll
        for (int t = 0; t < 2; ++t) {
            const int item = tid + t * 256;
            const int jh = item & 1, it2 = item >> 1;
            const int s = it2 >> 6, k8 = it2 & 63;
            float q[7], w0v[7][4];
            #pragma unroll
            for (int i = 0; i < 7; i++) {
                q[i] = sU.p.Q[s][i];
                float4 a = W04[i * 128 + k8 * 2 + jh];
                w0v[i][0] = a.x; w0v[i][1] = a.y; w0v[i][2] = a.z; w0v[i][3] = a.w;
            }
            float hv[4], dv[4];
            #pragma unroll
            for (int jj = 0; jj < 4; jj++) {
                float z = sU.p.B0[k8 * 8 + jh * 4 + jj];
                #pragma unroll
                for (int i = 0; i < 7; i++) z = fmaf(q[i], w0v[i][jj], z);
                float h = sig(z);
                hv[jj] = h; dv[jj] = h - h * h;
            }
            const int ktg = k8 >> 2, kq = k8 & 3;
            const int kxr = (kq << 4) ^ (kq << 1) ^ (ktg & 7);   // slot = kxr ^ (rr&15)
            const int rr0 = s * 8;
            st_pack4(&sA[((rr0 >> 4) * 16 + ktg) * 512 + (kxr ^ (rr0 & 15)) * 8 + jh * 4],
                     hv[0], hv[1], hv[2], hv[3]);
            #pragma unroll
            for (int i = 0; i < 7; i++) {
                const int rr = rr0 + 1 + i;
                st_pack4(&sA[((rr >> 4) * 16 + ktg) * 512 + (kxr ^ (rr & 15)) * 8 + jh * 4],
                         dv[0] * w0v[i][0], dv[1] * w0v[i][1], dv[2] * w0v[i][2], dv[3] * w0v[i][3]);
            }
        }
        __syncthreads();

        // ---- layer 1 MFMA, 2 ct-passes of 4, 16 kt contiguous, 3-buf rotation ----
        #pragma unroll
        for (int cp = 0; cp < 2; ++cp) {
            const int cp4 = cp * 4;
            if (cp) PLD(b0, 0);
            PLD(b1, 1); PLD(b2, 2);
            __builtin_amdgcn_s_setprio(1);
            PST(b0, 0);  PLD(b0, 3);
            PST(b1, 1);  PLD(b1, 4);
            PST(b2, 2);  PLD(b2, 5);
            PST(b0, 3);  PLD(b0, 6);
            PST(b1, 4);  PLD(b1, 7);
            PST(b2, 5);  PLD(b2, 8);
            PST(b0, 6);  PLD(b0, 9);
            PST(b1, 7);  PLD(b1, 10);
            PST(b2, 8);  PLD(b2, 11);
            PST(b0, 9);  PLD(b0, 12);
            PST(b1, 10); PLD(b1, 13);
            PST(b2, 11); PLD(b2, 14);
            PST(b0, 12); PLD(b0, 15);
            PST(b1, 13);
            PST(b2, 14);
            PST(b0, 15);
            __builtin_amdgcn_s_setprio(0);
        }
#undef PLD
#undef PST

        // T14: write epilogue params to LDS (covered by the ep barrier)
        sU.p.B1[tid] = b1r0; sU.p.B1[tid + 256] = b1r1;
        #pragma unroll
        for (int t = 0; t < 6; ++t) sU.p.W2[tid + 256 * t] = w2r[t];
        __syncthreads();                        // A-tile reads done + B1/W2 visible

        float ep[2][4][3];
        #pragma unroll
        for (int a = 0; a < 2; a++) for (int b = 0; b < 4; b++) for (int c = 0; c < 3; c++) ep[a][b][c] = 0.f;

        #pragma unroll
        for (int ct = 0; ct < 8; ++ct) {
            const int n = w * 128 + ct * 16 + col;
            const float b1n = sU.p.B1[n];
            const float w20 = sU.p.W2[n * 3], w21 = sU.p.W2[n * 3 + 1], w22 = sU.p.W2[n * 3 + 2];
            #pragma unroll
            for (int rt = 0; rt < 2; ++rt) {
                float z2c = __shfl(acc[rt][ct][0], srcl);
                float h2 = sig(z2c + b1n);
                float d2 = h2 - h2 * h2;
                #pragma unroll
                for (int r = 0; r < 4; ++r) {
                    float gg = ((quad & 1) == 0 && r == 0) ? h2 : d2 * acc[rt][ct][r];
                    ep[rt][r][0] = fmaf(gg, w20, ep[rt][r][0]);
                    ep[rt][r][1] = fmaf(gg, w21, ep[rt][r][1]);
                    ep[rt][r][2] = fmaf(gg, w22, ep[rt][r][2]);
                }
            }
        }

        // LDS-transpose reduce: partials [w][row][j][17] f32 in sA (A-tile dead)
        {
            float* pl = (float*)sA;
            #pragma unroll
            for (int rt = 0; rt < 2; ++rt)
                #pragma unroll
                for (int r = 0; r < 4; ++r) {
                    int row = rt * 16 + quad * 4 + r;
                    int base = ((w * 32 + row) * 3) * 17 + col;
                    pl[base]      = ep[rt][r][0];
                    pl[base + 17] = ep[rt][r][1];
                    pl[base + 34] = ep[rt][r][2];
                }
        }
        __syncthreads();

        if (tid < 96) {
            const float* pl = (const float*)sA;
            int row = tid / 3, j = tid % 3;
            float v = 0.f;
            #pragma unroll
            for (int ww = 0; ww < 4; ++ww) {
                const float* q = &pl[((ww * 32 + row) * 3 + j) * 17];
                #pragma unroll
                for (int c = 0; c < 16; ++c) v += q[c];
            }
            int s = row >> 3, i = row & 7;
            size_t M = m0 + s;
            if (i == 0) { v += pb2[j]; out[M * 18 + j] = v; out[OUTA + M * 6 + j] = v; }
            else        { out[JTOT + M * 63 + j * 7 + (i - 1)] = v;
                          out[JANG + M * 42 + j * 7 + (i - 1)] = v; }
            sU.p.Sum[row][j] = v;
        }
        __syncthreads();
        if (tid < 12) {
            int s = tid / 3, j = tid % 3;
            float vel = 0.f;
            #pragma unroll
            for (int i = 0; i < 7; i++) vel = fmaf(sU.p.Sum[s * 8 + 1 + i][j], sU.p.Qd[s][i], vel);
            out[(size_t)(m0 + s) * 18 + 9 + j] = vel;
        }
    } else {
        // ============ RPY: 7 -> 256 -> 256 -> 2, 8 samples (64 rows) ============
        const int h = r5 - 2;
        const int m0 = o * 8;
        const float* W0 = (h == 0) ? rW0_ : (h == 1) ? piW0 : yW0;
        const float* b0p = (h == 0) ? rb0_ : (h == 1) ? pib0 : yb0;
        const float* b1p = (h == 0) ? rb1_ : (h == 1) ? pib1 : yb1;
        const float* W2 = (h == 0) ? rW2_ : (h == 1) ? piW2 : yW2;
        const float* b2p = (h == 0) ? rb2_ : (h == 1) ? pib2 : yb2;
        const unsigned short* wsW1 = wsBase + 262144 + h * 65536;

        // T14: epilogue params straight into regs (consumed post-MFMA)
        const float b1r0 = b1p[tid];
        const float w2r0 = W2[tid], w2r1 = W2[tid + 256];

        if (tid < 256) sU.r.B0[tid] = b0p[tid];
        if (tid < 112) {
            int m = tid / 14, c = tid % 14;
            float v = x[(m0 + m) * 14 + c];
            if (c < 7) sU.r.Q[m][c] = v; else sU.r.Qd[m][c - 7] = v;
        }
        __syncthreads();

        const float4* W04 = (const float4*)W0;

        floatx4 acc[4][4];
        #pragma unroll
        for (int rt = 0; rt < 4; rt++)
            #pragma unroll
            for (int ct = 0; ct < 4; ct++) acc[rt][ct] = z4;

        const short8* bbase = (const short8*)wsW1 + (size_t)(w * 4 * 8) * 64 + lane;
        short8 b0[2], b1[2], b2[2];

#define RLD(B, KT) { \
            B[0] = bbase[((cp2 + 0) * 8 + (KT)) * 64]; \
            B[1] = bbase[((cp2 + 1) * 8 + (KT)) * 64]; }
#define RST(B, KT) { \
            const short8 a0 = *(const short8*)&sA[(0 * 8 + (KT)) * 512 + (lxk ^ (KT)) * 8]; \
            const short8 a1 = *(const short8*)&sA[(1 * 8 + (KT)) * 512 + (lxk ^ (KT)) * 8]; \
            const short8 a2 = *(const short8*)&sA[(2 * 8 + (KT)) * 512 + (lxk ^ (KT)) * 8]; \
            const short8 a3 = *(const short8*)&sA[(3 * 8 + (KT)) * 512 + (lxk ^ (KT)) * 8]; \
            acc[0][cp2 + 0] = __builtin_amdgcn_mfma_f32_16x16x32_bf16(a0, B[0], acc[0][cp2 + 0], 0, 0, 0); \
            acc[1][cp2 + 0] = __builtin_amdgcn_mfma_f32_16x16x32_bf16(a1, B[0], acc[1][cp2 + 0], 0, 0, 0); \
            acc[2][cp2 + 0] = __builtin_amdgcn_mfma_f32_16x16x32_bf16(a2, B[0], acc[2][cp2 + 0], 0, 0, 0); \
            acc[3][cp2 + 0] = __builtin_amdgcn_mfma_f32_16x16x32_bf16(a3, B[0], acc[3][cp2 + 0], 0, 0, 0); \
            acc[0][cp2 + 1] = __builtin_amdgcn_mfma_f32_16x16x32_bf16(a0, B[1], acc[0][cp2 + 1], 0, 0, 0); \
            acc[1][cp2 + 1] = __builtin_amdgcn_mfma_f32_16x16x32_bf16(a1, B[1], acc[1][cp2 + 1], 0, 0, 0); \
            acc[2][cp2 + 1] = __builtin_amdgcn_mfma_f32_16x16x32_bf16(a2, B[1], acc[2][cp2 + 1], 0, 0, 0); \
            acc[3][cp2 + 1] = __builtin_amdgcn_mfma_f32_16x16x32_bf16(a3, B[1], acc[3][cp2 + 1], 0, 0, 0); }

        {
            // T14: cp0's first fragment set, issued before L0 (independent of sA)
            const int cp2 = 0;
            RLD(b0, 0);
        }

        // ---- layer 0, full K: 512 items (8 samples x 32 k8 x 2 jj-halves) ----
        #pragma unroll
        for (int t = 0; t < 2; ++t) {
            const int item = tid + t * 256;
            const int jh = item & 1, it2 = item >> 1;
            const int s = it2 >> 5, k8 = it2 & 31;
            float q[7], w0v[7][4];
            #pragma unroll
            for (int i = 0; i < 7; i++) {
                q[i] = sU.r.Q[s][i];
                float4 a = W04[i * 64 + k8 * 2 + jh];
                w0v[i][0] = a.x; w0v[i][1] = a.y; w0v[i][2] = a.z; w0v[i][3] = a.w;
            }
            float hv[4], dv[4];
            #pragma unroll
            for (int jj = 0; jj < 4; jj++) {
                float z = sU.r.B0[k8 * 8 + jh * 4 + jj];
                #pragma unroll
                for (int i = 0; i < 7; i++) z = fmaf(q[i], w0v[i][jj], z);
                float hhh = sig(z);
                hv[jj] = hhh; dv[jj] = hhh - hhh * hhh;
            }
            const int ktg = k8 >> 2, kq = k8 & 3;
            const int kxr = (kq << 4) ^ (kq << 1) ^ ktg;     // slot = kxr ^ (rr&15)
            const int rr0 = s * 8;
            st_pack4(&sA[((rr0 >> 4) * 8 + ktg) * 512 + (kxr ^ (rr0 & 15)) * 8 + jh * 4],
                     hv[0], hv[1], hv[2], hv[3]);
            #pragma unroll
            for (int i = 0; i < 7; i++) {
                const int rr = rr0 + 1 + i;
                st_pack4(&sA[((rr >> 4) * 8 + ktg) * 512 + (kxr ^ (rr & 15)) * 8 + jh * 4],
                         dv[0] * w0v[i][0], dv[1] * w0v[i][1], dv[2] * w0v[i][2], dv[3] * w0v[i][3]);
            }
        }
        __syncthreads();

        // ---- layer 1 MFMA, 2 ct-passes of 2, 8 kt contiguous, 3-buf rotation ----
        #pragma unroll
        for (int cp = 0; cp < 2; ++cp) {
            const int cp2 = cp * 2;
            if (cp) RLD(b0, 0);
            RLD(b1, 1); RLD(b2, 2);
            __builtin_amdgcn_s_setprio(1);
            RST(b0, 0); RLD(b0, 3);
            RST(b1, 1); RLD(b1, 4);
            RST(b2, 2); RLD(b2, 5);
            RST(b0, 3); RLD(b0, 6);
            RST(b1, 4); RLD(b1, 7);
            RST(b2, 5);
            RST(b0, 6);
            RST(b1, 7);
            __builtin_amdgcn_s_setprio(0);
        }
#undef RLD
#undef RST

        // T14: write epilogue params to LDS (covered by the ep barrier)
        sU.r.B1[tid] = b1r0;
        sU.r.W2[tid] = w2r0; sU.r.W2[tid + 256] = w2r1;
        __syncthreads();                        // A-tile reads done + B1/W2 visible

        float ep[4][4][2];
        #pragma unroll
        for (int a = 0; a < 4; a++) for (int b = 0; b < 4; b++) for (int c = 0; c < 2; c++) ep[a][b][c] = 0.f;

        #pragma unroll
        for (int ct = 0; ct < 4; ++ct) {
            const int n = w * 64 + ct * 16 + col;
            const float b1n = sU.r.B1[n];
            const float w20 = sU.r.W2[n * 2], w21 = sU.r.W2[n * 2 + 1];
            #pragma unroll
            for (int rt = 0; rt < 4; ++rt) {
                float z2c = __shfl(acc[rt][ct][0], srcl);
                float h2 = sig(z2c + b1n);
                float d2 = h2 - h2 * h2;
                #pragma unroll
                for (int r = 0; r < 4; ++r) {
                    float gg = ((quad & 1) == 0 && r == 0) ? h2 : d2 * acc[rt][ct][r];
                    ep[rt][r][0] = fmaf(gg, w20, ep[rt][r][0]);
                    ep[rt][r][1] = fmaf(gg, w21, ep[rt][r][1]);
                }
            }
        }

        // LDS-transpose reduce: partials [w][row][j][17] f32 in sA (A-tile dead)
        {
            float* pl = (float*)sA;
            #pragma unroll
            for (int rt = 0; rt < 4; ++rt)
                #pragma unroll
                for (int r = 0; r < 4; ++r) {
                    int row = rt * 16 + quad * 4 + r;
                    int base = ((w * 64 + row) * 2) * 17 + col;
                    pl[base]      = ep[rt][r][0];
                    pl[base + 17] = ep[rt][r][1];
                }
        }
        __syncthreads();

        if (tid < 128) {
            const float* pl = (const float*)sA;
            int row = tid >> 1, j = tid & 1;
            float v = 0.f;
            #pragma unroll
            for (int ww = 0; ww < 4; ++ww) {
                const float* q = &pl[((ww * 64 + row) * 2 + j) * 17];
                #pragma unroll
                for (int c = 0; c < 16; ++c) v += q[c];
            }
            if ((row & 7) == 0) v += b2p[j];
            sU.r.Sum[row][j] = v;
        }
        __syncthreads();

        if (tid < 8) {
            int s = tid;
            size_t M = m0 + s;
            float y0 = sU.r.Sum[s * 8][0], y1 = sU.r.Sum[s * 8][1];
            float sv = sinf(y0), cv = cosf(y1);
            out[M * 18 + 3 + h] = sv;
            out[M * 18 + 6 + h] = cv;
            out[OUTA + M * 6 + 3 + h] = atan2f(sv, cv);
            float f0 = cosf(y0), f1 = -sinf(y1);
            float inv = 1.0f / fmaf(sv, sv, cv * cv);
            float v0 = 0.f, v1 = 0.f;
            #pragma unroll
            for (int i = 0; i < 7; i++) {
                float r0 = f0 * sU.r.Sum[s * 8 + 1 + i][0];
                float r1 = f1 * sU.r.Sum[s * 8 + 1 + i][1];
                out[JTOT + M * 63 + (3 + h) * 7 + i] = r0;
                out[JTOT + M * 63 + (6 + h) * 7 + i] = r1;
                out[JANG + M * 42 + (3 + h) * 7 + i] = (cv * r0 - sv * r1) * inv;
                v0 = fmaf(r0, sU.r.Qd[s][i], v0);
                v1 = fmaf(r1, sU.r.Qd[s][i], v1);
            }
            out[M * 18 + 12 + h] = v0;
            out[M * 18 + 15 + h] = v1;
        }
    }
}

extern "C" void kernel_launch(void* const* d_in, const int* in_sizes, int n_in,
                              void* d_out, int out_size, void* d_ws, size_t ws_size,
                              hipStream_t stream) {
    (void)n_in; (void)out_size; (void)ws_size;
    const float* x = (const float*)d_in[0];
    float* out = (float*)d_out;
    unsigned short* ws = (unsigned short*)d_ws;
    const int ns = in_sizes[0] / 14;

    convert_all<<<dim3(1792), 256, 0, stream>>>(
        (const float*)d_in[3], (const float*)d_in[9],
        (const float*)d_in[15], (const float*)d_in[21], ws);

    // 10240 blocks (2048 octets x 5 roles); 34816B dynamic LDS
    fused_mfma<<<dim3((ns / 8) * 5), 256, 34816, stream>>>(
        x,
        (const float*)d_in[1],  (const float*)d_in[2],  (const float*)d_in[4],
        (const float*)d_in[5],  (const float*)d_in[6],
        (const float*)d_in[7],  (const float*)d_in[8],  (const float*)d_in[10],
        (const float*)d_in[11], (const float*)d_in[12],
        (const float*)d_in[13], (const float*)d_in[14], (const float*)d_in[16],
        (const float*)d_in[17], (const float*)d_in[18],
        (const float*)d_in[19], (const float*)d_in[20], (const float*)d_in[22],
        (const float*)d_in[23], (const float*)d_in[24],
        ws, out, ns);
}

// Round 8
// 282.995 us; speedup vs baseline: 1.0196x; 1.0137x over previous
//
#include <hip/hip_runtime.h>
#include <math.h>

typedef __attribute__((ext_vector_type(8))) short short8;
typedef __attribute__((ext_vector_type(4))) float floatx4;
typedef __attribute__((ext_vector_type(2))) unsigned uint2v;

__device__ __forceinline__ float sig(float z) { return 1.0f / (1.0f + __expf(-z)); }

__device__ __forceinline__ unsigned short f2bf(float f) {
    unsigned u = __float_as_uint(f);
    u = (u + 0x7FFFu + ((u >> 16) & 1u)) >> 16;   // RNE
    return (unsigned short)u;
}

// v_cvt_pk_bf16_f32: packs 2 f32 -> 2 bf16 (RNE) in one instruction.
__device__ __forceinline__ unsigned cvtpk_bf16(float lo, float hi) {
    unsigned r;
    asm("v_cvt_pk_bf16_f32 %0, %1, %2" : "=v"(r) : "v"(lo), "v"(hi));
    return r;
}

// 4 floats -> 4 bf16 (8B store), RNE identical to f2bf.
__device__ __forceinline__ void st_pack4(unsigned short* p, float v0, float v1, float v2, float v3) {
    uint2v u;
    u.x = cvtpk_bf16(v0, v1);
    u.y = cvtpk_bf16(v2, v3);
    *(uint2v*)p = u;
}

// All four W1 matrices -> bf16 pre-swizzled MFMA 16x16x32 B-frag order.
// blk = (n>>4)*(H/32) + (k>>5), lane = ((k>>3)&3)*16 + (n&15), j = k&7.
__global__ void convert_all(const float* __restrict__ s0, const float* __restrict__ s1,
                            const float* __restrict__ s2, const float* __restrict__ s3,
                            unsigned short* __restrict__ ws) {
    int idx = blockIdx.x * 256 + threadIdx.x;          // 0 .. 458751
    const float* src; unsigned short* dst; int H, logH, local;
    if (idx < 262144) { src = s0; dst = ws; H = 512; logH = 9; local = idx; }
    else {
        int r = idx - 262144; int m = r >> 16; local = r & 65535;
        H = 256; logH = 8;
        src = (m == 0) ? s1 : (m == 1) ? s2 : s3;
        dst = ws + 262144 + m * 65536;
    }
    int n = local & (H - 1), k = local >> logH;
    int KT = H >> 5;
    int blk = (n >> 4) * KT + (k >> 5);
    int lane = ((k >> 3) & 3) * 16 + (n & 15);
    int j = k & 7;
    dst[(blk * 64 + lane) * 8 + j] = f2bf(src[local]);
}

// R8 = exact R6 structure (best measured: 203.8us fused; R7's phase-merge
// REGRESSED to 218.5 -> split-K retained: it provides cross-block phase
// stagger for pipe overlap) + the one orthogonal R7 piece, isolated:
//  - T14 param-hoist: B1/W2 held in regs from block start (pos 8, rpy 3),
//    written to LDS after the MFMA phase; the pre-partials barrier moves to
//    before ep-compute (covers A-tile-reads-done AND B1/W2 visibility).
//    First barrier waits on ~550 floats (B0+Q), was ~2600.
//  - Barrier count unchanged vs R6; numerics bit-identical.
// Sentinels: VGPR <= ~110, FETCH ~4.5MB (R2 spill lesson).
struct PosS {
    float B0[512], B1[512], W2[1536];
    float Q[4][8], Qd[4][8];
    float Sum[32][3];
};
struct RpyS {
    float B0[256], B1[256], W2[512];
    float Q[8][8], Qd[8][8];
    float Sum[64][2];
};

__global__ __launch_bounds__(256, 3)
void fused_mfma(const float* __restrict__ x,
                const float* __restrict__ pW0, const float* __restrict__ pb0,
                const float* __restrict__ pb1,
                const float* __restrict__ pW2, const float* __restrict__ pb2,
                const float* __restrict__ rW0_, const float* __restrict__ rb0_,
                const float* __restrict__ rb1_,
                const float* __restrict__ rW2_, const float* __restrict__ rb2_,
                const float* __restrict__ piW0, const float* __restrict__ pib0,
                const float* __restrict__ pib1,
                const float* __restrict__ piW2, const float* __restrict__ pib2,
                const float* __restrict__ yW0, const float* __restrict__ yb0,
                const float* __restrict__ yb1,
                const float* __restrict__ yW2, const float* __restrict__ yb2,
                const unsigned short* __restrict__ wsBase,
                float* __restrict__ out, int ns)
{
    extern __shared__ unsigned short sA[];      // 34816B: A-tile (16KB) then f32 partials
    __shared__ union { PosS p; RpyS r; } sU;

    const int tid = threadIdx.x;
    const int xcd  = blockIdx.x & 7;
    const int slot = blockIdx.x >> 3;           // 0..1279 within this XCD
    const int o_l  = slot / 5, r5 = slot % 5;
    const int o = xcd + (o_l << 3);             // sample-octet 0..2047

    const size_t JTOT = (size_t)ns * 18, OUTA = (size_t)ns * 81, JANG = (size_t)ns * 87;
    const floatx4 z4 = {0.f, 0.f, 0.f, 0.f};
    const int w = tid >> 6, lane = tid & 63;
    const int quad = lane >> 4, col = lane & 15;
    const int srcl = lane & 47;
    const int lxk = lane ^ (quad << 1);         // kq-swizzled read index

    if (r5 < 2) {
        // ============ POS: 7 -> 512 -> 512 -> 3, 4 samples (32 rows) ============
        const int m0 = (o * 2 + r5) * 4;
        const unsigned short* wsW1 = wsBase;

        // T14: epilogue params straight into regs (LDS-written post-MFMA)
        const float b1r0 = pb1[tid], b1r1 = pb1[tid + 256];
        float w2r[6];
        #pragma unroll
        for (int t = 0; t < 6; ++t) w2r[t] = pW2[tid + 256 * t];

        for (int i = tid; i < 512; i += 256) sU.p.B0[i] = pb0[i];
        if (tid < 56) {
            int m = tid / 14, c = tid % 14;
            float v = x[(m0 + m) * 14 + c];
            if (c < 7) sU.p.Q[m][c] = v; else sU.p.Qd[m][c - 7] = v;
        }
        __syncthreads();

        const float4* W04 = (const float4*)pW0;

        floatx4 acc[2][8];
        #pragma unroll
        for (int rt = 0; rt < 2; rt++)
            #pragma unroll
            for (int ct = 0; ct < 8; ct++) acc[rt][ct] = z4;

        const short8* bbase = (const short8*)wsW1 + (size_t)(w * 8 * 16) * 64 + lane;
        short8 b0[4], b1[4], b2[4];

#define PLD(B, KT) { \
            B[0] = bbase[((cp4 + 0) * 16 + hh8 + (KT)) * 64]; \
            B[1] = bbase[((cp4 + 1) * 16 + hh8 + (KT)) * 64]; \
            B[2] = bbase[((cp4 + 2) * 16 + hh8 + (KT)) * 64]; \
            B[3] = bbase[((cp4 + 3) * 16 + hh8 + (KT)) * 64]; }
#define PST(B, KT) { \
            const short8 a0 = *(const short8*)&sA[(0 * 8 + (KT)) * 512 + (lxk ^ (KT)) * 8]; \
            const short8 a1 = *(const short8*)&sA[(1 * 8 + (KT)) * 512 + (lxk ^ (KT)) * 8]; \
            acc[0][cp4 + 0] = __builtin_amdgcn_mfma_f32_16x16x32_bf16(a0, B[0], acc[0][cp4 + 0], 0, 0, 0); \
            acc[1][cp4 + 0] = __builtin_amdgcn_mfma_f32_16x16x32_bf16(a1, B[0], acc[1][cp4 + 0], 0, 0, 0); \
            acc[0][cp4 + 1] = __builtin_amdgcn_mfma_f32_16x16x32_bf16(a0, B[1], acc[0][cp4 + 1], 0, 0, 0); \
            acc[1][cp4 + 1] = __builtin_amdgcn_mfma_f32_16x16x32_bf16(a1, B[1], acc[1][cp4 + 1], 0, 0, 0); \
            acc[0][cp4 + 2] = __builtin_amdgcn_mfma_f32_16x16x32_bf16(a0, B[2], acc[0][cp4 + 2], 0, 0, 0); \
            acc[1][cp4 + 2] = __builtin_amdgcn_mfma_f32_16x16x32_bf16(a1, B[2], acc[1][cp4 + 2], 0, 0, 0); \
            acc[0][cp4 + 3] = __builtin_amdgcn_mfma_f32_16x16x32_bf16(a0, B[3], acc[0][cp4 + 3], 0, 0, 0); \
            acc[1][cp4 + 3] = __builtin_amdgcn_mfma_f32_16x16x32_bf16(a1, B[3], acc[1][cp4 + 3], 0, 0, 0); }

        #pragma unroll
        for (int hh = 0; hh < 2; ++hh) {
            const int hh8 = hh * 8;
            // T14: cp0's first fragment set, issued before L0 (independent of sA)
            b0[0] = bbase[(0 * 16 + hh8) * 64];
            b0[1] = bbase[(1 * 16 + hh8) * 64];
            b0[2] = bbase[(2 * 16 + hh8) * 64];
            b0[3] = bbase[(3 * 16 + hh8) * 64];
            // ---- layer 0, K-half hh: 256 threads = 4 samples x 32 k8 x 2 jj-halves ----
            {
                const int jh = tid & 1, item = tid >> 1;
                const int s = item >> 5, k8l = item & 31, k8 = (hh << 5) | k8l;
                float q[7], w0v[7][4];
                #pragma unroll
                for (int i = 0; i < 7; i++) {
                    q[i] = sU.p.Q[s][i];
                    float4 a = W04[i * 128 + k8 * 2 + jh];
                    w0v[i][0] = a.x; w0v[i][1] = a.y; w0v[i][2] = a.z; w0v[i][3] = a.w;
                }
                float hv[4], dv[4];
                #pragma unroll
                for (int jj = 0; jj < 4; jj++) {
                    float z = sU.p.B0[k8 * 8 + jh * 4 + jj];
                    #pragma unroll
                    for (int i = 0; i < 7; i++) z = fmaf(q[i], w0v[i][jj], z);
                    float h = sig(z);
                    hv[jj] = h; dv[jj] = h - h * h;
                }
                const int ktl = k8l >> 2, kq = k8l & 3;
                const int kxr = (kq << 4) ^ (kq << 1) ^ ktl;   // slot = kxr ^ (rr&15)
                const int rr0 = s * 8;
                st_pack4(&sA[((rr0 >> 4) * 8 + ktl) * 512 + (kxr ^ (rr0 & 15)) * 8 + jh * 4],
                         hv[0], hv[1], hv[2], hv[3]);
                #pragma unroll
                for (int i = 0; i < 7; i++) {
                    const int rr = rr0 + 1 + i;
                    st_pack4(&sA[((rr >> 4) * 8 + ktl) * 512 + (kxr ^ (rr & 15)) * 8 + jh * 4],
                             dv[0] * w0v[i][0], dv[1] * w0v[i][1], dv[2] * w0v[i][2], dv[3] * w0v[i][3]);
                }
            }
            __syncthreads();

            // ---- layer 1 MFMA over this K-half, 2 ct-passes of 4, 3-buf rotation ----
            #pragma unroll
            for (int cp = 0; cp < 2; ++cp) {
                const int cp4 = cp * 4;
                if (cp) PLD(b0, 0);
                PLD(b1, 1); PLD(b2, 2);
                __builtin_amdgcn_s_setprio(1);
                PST(b0, 0); PLD(b0, 3);
                PST(b1, 1); PLD(b1, 4);
                PST(b2, 2); PLD(b2, 5);
                PST(b0, 3); PLD(b0, 6);
                PST(b1, 4); PLD(b1, 7);
                PST(b2, 5);
                PST(b0, 6);
                PST(b1, 7);
                __builtin_amdgcn_s_setprio(0);
            }
            if (hh == 0) __syncthreads();   // drain reads before half-1 overwrites sA
        }
#undef PLD
#undef PST

        // T14: write epilogue params to LDS; barrier also closes A-tile reads
        sU.p.B1[tid] = b1r0; sU.p.B1[tid + 256] = b1r1;
        #pragma unroll
        for (int t = 0; t < 6; ++t) sU.p.W2[tid + 256 * t] = w2r[t];
        __syncthreads();

        float ep[2][4][3];
        #pragma unroll
        for (int a = 0; a < 2; a++) for (int b = 0; b < 4; b++) for (int c = 0; c < 3; c++) ep[a][b][c] = 0.f;

        #pragma unroll
        for (int ct = 0; ct < 8; ++ct) {
            const int n = w * 128 + ct * 16 + col;
            const float b1n = sU.p.B1[n];
            const float w20 = sU.p.W2[n * 3], w21 = sU.p.W2[n * 3 + 1], w22 = sU.p.W2[n * 3 + 2];
            #pragma unroll
            for (int rt = 0; rt < 2; ++rt) {
                float z2c = __shfl(acc[rt][ct][0], srcl);
                float h2 = sig(z2c + b1n);
                float d2 = h2 - h2 * h2;
                #pragma unroll
                for (int r = 0; r < 4; ++r) {
                    float gg = ((quad & 1) == 0 && r == 0) ? h2 : d2 * acc[rt][ct][r];
                    ep[rt][r][0] = fmaf(gg, w20, ep[rt][r][0]);
                    ep[rt][r][1] = fmaf(gg, w21, ep[rt][r][1]);
                    ep[rt][r][2] = fmaf(gg, w22, ep[rt][r][2]);
                }
            }
        }

        // LDS-transpose reduce: partials [w][row][j][17] f32 in sA (A-tile dead)
        {
            float* pl = (float*)sA;
            #pragma unroll
            for (int rt = 0; rt < 2; ++rt)
                #pragma unroll
                for (int r = 0; r < 4; ++r) {
                    int row = rt * 16 + quad * 4 + r;
                    int base = ((w * 32 + row) * 3) * 17 + col;
                    pl[base]      = ep[rt][r][0];
                    pl[base + 17] = ep[rt][r][1];
                    pl[base + 34] = ep[rt][r][2];
                }
        }
        __syncthreads();

        if (tid < 96) {
            const float* pl = (const float*)sA;
            int row = tid / 3, j = tid % 3;
            float v = 0.f;
            #pragma unroll
            for (int ww = 0; ww < 4; ++ww) {
                const float* q = &pl[((ww * 32 + row) * 3 + j) * 17];
                #pragma unroll
                for (int c = 0; c < 16; ++c) v += q[c];
            }
            int s = row >> 3, i = row & 7;
            size_t M = m0 + s;
            if (i == 0) { v += pb2[j]; out[M * 18 + j] = v; out[OUTA + M * 6 + j] = v; }
            else        { out[JTOT + M * 63 + j * 7 + (i - 1)] = v;
                          out[JANG + M * 42 + j * 7 + (i - 1)] = v; }
            sU.p.Sum[row][j] = v;
        }
        __syncthreads();
        if (tid < 12) {
            int s = tid / 3, j = tid % 3;
            float vel = 0.f;
            #pragma unroll
            for (int i = 0; i < 7; i++) vel = fmaf(sU.p.Sum[s * 8 + 1 + i][j], sU.p.Qd[s][i], vel);
            out[(size_t)(m0 + s) * 18 + 9 + j] = vel;
        }
    } else {
        // ============ RPY: 7 -> 256 -> 256 -> 2, 8 samples (64 rows) ============
        const int h = r5 - 2;
        const int m0 = o * 8;
        const float* W0 = (h == 0) ? rW0_ : (h == 1) ? piW0 : yW0;
        const float* b0p = (h == 0) ? rb0_ : (h == 1) ? pib0 : yb0;
        const float* b1p = (h == 0) ? rb1_ : (h == 1) ? pib1 : yb1;
        const float* W2 = (h == 0) ? rW2_ : (h == 1) ? piW2 : yW2;
        const float* b2p = (h == 0) ? rb2_ : (h == 1) ? pib2 : yb2;
        const unsigned short* wsW1 = wsBase + 262144 + h * 65536;

        // T14: epilogue params straight into regs (LDS-written post-MFMA)
        const float b1r0 = b1p[tid];
        const float w2r0 = W2[tid], w2r1 = W2[tid + 256];

        if (tid < 256) sU.r.B0[tid] = b0p[tid];
        if (tid < 112) {
            int m = tid / 14, c = tid % 14;
            float v = x[(m0 + m) * 14 + c];
            if (c < 7) sU.r.Q[m][c] = v; else sU.r.Qd[m][c - 7] = v;
        }
        __syncthreads();

        const float4* W04 = (const float4*)W0;

        floatx4 acc[4][4];
        #pragma unroll
        for (int rt = 0; rt < 4; rt++)
            #pragma unroll
            for (int ct = 0; ct < 4; ct++) acc[rt][ct] = z4;

        const short8* bbase = (const short8*)wsW1 + (size_t)(w * 4 * 8) * 64 + lane;
        short8 b0[2], b1[2], b2[2];

#define RLD(B, KT) { \
            B[0] = bbase[((cp2 + 0) * 8 + hh4 + (KT)) * 64]; \
            B[1] = bbase[((cp2 + 1) * 8 + hh4 + (KT)) * 64]; }
#define RST(B, KT) { \
            const int sw_ = hh4 + (KT); \
            const short8 a0 = *(const short8*)&sA[(0 * 4 + (KT)) * 512 + (lxk ^ sw_) * 8]; \
            const short8 a1 = *(const short8*)&sA[(1 * 4 + (KT)) * 512 + (lxk ^ sw_) * 8]; \
            const short8 a2 = *(const short8*)&sA[(2 * 4 + (KT)) * 512 + (lxk ^ sw_) * 8]; \
            const short8 a3 = *(const short8*)&sA[(3 * 4 + (KT)) * 512 + (lxk ^ sw_) * 8]; \
            acc[0][cp2 + 0] = __builtin_amdgcn_mfma_f32_16x16x32_bf16(a0, B[0], acc[0][cp2 + 0], 0, 0, 0); \
            acc[1][cp2 + 0] = __builtin_amdgcn_mfma_f32_16x16x32_bf16(a1, B[0], acc[1][cp2 + 0], 0, 0, 0); \
            acc[2][cp2 + 0] = __builtin_amdgcn_mfma_f32_16x16x32_bf16(a2, B[0], acc[2][cp2 + 0], 0, 0, 0); \
            acc[3][cp2 + 0] = __builtin_amdgcn_mfma_f32_16x16x32_bf16(a3, B[0], acc[3][cp2 + 0], 0, 0, 0); \
            acc[0][cp2 + 1] = __builtin_amdgcn_mfma_f32_16x16x32_bf16(a0, B[1], acc[0][cp2 + 1], 0, 0, 0); \
            acc[1][cp2 + 1] = __builtin_amdgcn_mfma_f32_16x16x32_bf16(a1, B[1], acc[1][cp2 + 1], 0, 0, 0); \
            acc[2][cp2 + 1] = __builtin_amdgcn_mfma_f32_16x16x32_bf16(a2, B[1], acc[2][cp2 + 1], 0, 0, 0); \
            acc[3][cp2 + 1] = __builtin_amdgcn_mfma_f32_16x16x32_bf16(a3, B[1], acc[3][cp2 + 1], 0, 0, 0); }

        #pragma unroll
        for (int hh = 0; hh < 2; ++hh) {
            const int hh4 = hh * 4;
            // T14: cp0's first fragment set, issued before L0 (independent of sA)
            b0[0] = bbase[(0 * 8 + hh4) * 64];
            b0[1] = bbase[(1 * 8 + hh4) * 64];
            // ---- layer 0, K-half hh: 256 threads = 8 samples x 16 k8 x 2 jj-halves ----
            {
                const int jh = tid & 1, item = tid >> 1;
                const int s = item >> 4, k8l = item & 15, k8 = (hh << 4) | k8l;
                float q[7], w0v[7][4];
                #pragma unroll
                for (int i = 0; i < 7; i++) {
                    q[i] = sU.r.Q[s][i];
                    float4 a = W04[i * 64 + k8 * 2 + jh];
                    w0v[i][0] = a.x; w0v[i][1] = a.y; w0v[i][2] = a.z; w0v[i][3] = a.w;
                }
                float hv[4], dv[4];
                #pragma unroll
                for (int jj = 0; jj < 4; jj++) {
                    float z = sU.r.B0[k8 * 8 + jh * 4 + jj];
                    #pragma unroll
                    for (int i = 0; i < 7; i++) z = fmaf(q[i], w0v[i][jj], z);
                    float hhh = sig(z);
                    hv[jj] = hhh; dv[jj] = hhh - hhh * hhh;
                }
                const int ktl = k8l >> 2, kq = k8l & 3;
                const int sw = (hh << 2) | ktl;              // global kt & 7
                const int kxr = (kq << 4) ^ (kq << 1) ^ sw;  // slot = kxr ^ (rr&15)
                const int rr0 = s * 8;
                st_pack4(&sA[((rr0 >> 4) * 4 + ktl) * 512 + (kxr ^ (rr0 & 15)) * 8 + jh * 4],
                         hv[0], hv[1], hv[2], hv[3]);
                #pragma unroll
                for (int i = 0; i < 7; i++) {
                    const int rr = rr0 + 1 + i;
                    st_pack4(&sA[((rr >> 4) * 4 + ktl) * 512 + (kxr ^ (rr & 15)) * 8 + jh * 4],
                             dv[0] * w0v[i][0], dv[1] * w0v[i][1], dv[2] * w0v[i][2], dv[3] * w0v[i][3]);
                }
            }
            __syncthreads();

            // ---- layer 1 MFMA over this K-half, 2 ct-passes of 2, 3-buf rotation ----
            #pragma unroll
            for (int cp = 0; cp < 2; ++cp) {
                const int cp2 = cp * 2;
                if (cp) RLD(b0, 0);
                RLD(b1, 1); RLD(b2, 2);
                __builtin_amdgcn_s_setprio(1);
                RST(b0, 0); RLD(b0, 3);
                RST(b1, 1);
                RST(b2, 2);
                RST(b0, 3);
                __builtin_amdgcn_s_setprio(0);
            }
            if (hh == 0) __syncthreads();   // drain reads before half-1 overwrites sA
        }
#undef RLD
#undef RST

        // T14: write epilogue params to LDS; barrier also closes A-tile reads
        sU.r.B1[tid] = b1r0;
        sU.r.W2[tid] = w2r0; sU.r.W2[tid + 256] = w2r1;
        __syncthreads();

        float ep[4][4][2];
        #pragma unroll
        for (int a = 0; a < 4; a++) for (int b = 0; b < 4; b++) for (int c = 0; c < 2; c++) ep[a][b][c] = 0.f;

        #pragma unroll
        for (int ct = 0; ct < 4; ++ct) {
            const int n = w * 64 + ct * 16 + col;
            const float b1n = sU.r.B1[n];
            const float w20 = sU.r.W2[n * 2], w21 = sU.r.W2[n * 2 + 1];
            #pragma unroll
            for (int rt = 0; rt < 4; ++rt) {
                float z2c = __shfl(acc[rt][ct][0], srcl);
                float h2 = sig(z2c + b1n);
                float d2 = h2 - h2 * h2;
                #pragma unroll
                for (int r = 0; r < 4; ++r) {
                    float gg = ((quad & 1) == 0 && r == 0) ? h2 : d2 * acc[rt][ct][r];
                    ep[rt][r][0] = fmaf(gg, w20, ep[rt][r][0]);
                    ep[rt][r][1] = fmaf(gg, w21, ep[rt][r][1]);
                }
            }
        }

        // LDS-transpose reduce: partials [w][row][j][17] f32 in sA (A-tile dead)
        {
            float* pl = (float*)sA;
            #pragma unroll
            for (int rt = 0; rt < 4; ++rt)
                #pragma unroll
                for (int r = 0; r < 4; ++r) {
                    int row = rt * 16 + quad * 4 + r;
                    int base = ((w * 64 + row) * 2) * 17 + col;
                    pl[base]      = ep[rt][r][0];
                    pl[base + 17] = ep[rt][r][1];
                }
        }
        __syncthreads();

        if (tid < 128) {
            const float* pl = (const float*)sA;
            int row = tid >> 1, j = tid & 1;
            float v = 0.f;
            #pragma unroll
            for (int ww = 0; ww < 4; ++ww) {
                const float* q = &pl[((ww * 64 + row) * 2 + j) * 17];
                #pragma unroll
                for (int c = 0; c < 16; ++c) v += q[c];
            }
            if ((row & 7) == 0) v += b2p[j];
            sU.r.Sum[row][j] = v;
        }
        __syncthreads();

        if (tid < 8) {
            int s = tid;
            size_t M = m0 + s;
            float y0 = sU.r.Sum[s * 8][0], y1 = sU.r.Sum[s * 8][1];
            float sv = sinf(y0), cv = cosf(y1);
            out[M * 18 + 3 + h] = sv;
            out[M * 18 + 6 + h] = cv;
            out[OUTA + M * 6 + 3 + h] = atan2f(sv, cv);
            float f0 = cosf(y0), f1 = -sinf(y1);
            float inv = 1.0f / fmaf(sv, sv, cv * cv);
            float v0 = 0.f, v1 = 0.f;
            #pragma unroll
            for (int i = 0; i < 7; i++) {
                float r0 = f0 * sU.r.Sum[s * 8 + 1 + i][0];
                float r1 = f1 * sU.r.Sum[s * 8 + 1 + i][1];
                out[JTOT + M * 63 + (3 + h) * 7 + i] = r0;
                out[JTOT + M * 63 + (6 + h) * 7 + i] = r1;
                out[JANG + M * 42 + (3 + h) * 7 + i] = (cv * r0 - sv * r1) * inv;
                v0 = fmaf(r0, sU.r.Qd[s][i], v0);
                v1 = fmaf(r1, sU.r.Qd[s][i], v1);
            }
            out[M * 18 + 12 + h] = v0;
            out[M * 18 + 15 + h] = v1;
        }
    }
}

extern "C" void kernel_launch(void* const* d_in, const int* in_sizes, int n_in,
                              void* d_out, int out_size, void* d_ws, size_t ws_size,
                              hipStream_t stream) {
    (void)n_in; (void)out_size; (void)ws_size;
    const float* x = (const float*)d_in[0];
    float* out = (float*)d_out;
    unsigned short* ws = (unsigned short*)d_ws;
    const int ns = in_sizes[0] / 14;

    convert_all<<<dim3(1792), 256, 0, stream>>>(
        (const float*)d_in[3], (const float*)d_in[9],
        (const float*)d_in[15], (const float*)d_in[21], ws);

    // 10240 blocks (2048 octets x 5 roles); 34816B dynamic LDS
    fused_mfma<<<dim3((ns / 8) * 5), 256, 34816, stream>>>(
        x,
        (const float*)d_in[1],  (const float*)d_in[2],  (const float*)d_in[4],
        (const float*)d_in[5],  (const float*)d_in[6],
        (const float*)d_in[7],  (const float*)d_in[8],  (const float*)d_in[10],
        (const float*)d_in[11], (const float*)d_in[12],
        (const float*)d_in[13], (const float*)d_in[14], (const float*)d_in[16],
        (const float*)d_in[17], (const float*)d_in[18],
        (const float*)d_in[19], (const float*)d_in[20], (const float*)d_in[22],
        (const float*)d_in[23], (const float*)d_in[24],
        ws, out, ns);
}

// Round 9
// 277.660 us; speedup vs baseline: 1.0392x; 1.0192x over previous
//
#include <hip/hip_runtime.h>
#include <math.h>

typedef __attribute__((ext_vector_type(8))) short short8;
typedef __attribute__((ext_vector_type(4))) float floatx4;
typedef __attribute__((ext_vector_type(2))) float floatx2;
typedef __attribute__((ext_vector_type(2))) unsigned uint2v;

__device__ __forceinline__ float sig(float z) { return 1.0f / (1.0f + __expf(-z)); }

__device__ __forceinline__ unsigned short f2bf(float f) {
    unsigned u = __float_as_uint(f);
    u = (u + 0x7FFFu + ((u >> 16) & 1u)) >> 16;   // RNE
    return (unsigned short)u;
}

// v_cvt_pk_bf16_f32: packs 2 f32 -> 2 bf16 (RNE) in one instruction.
__device__ __forceinline__ unsigned cvtpk_bf16(float lo, float hi) {
    unsigned r;
    asm("v_cvt_pk_bf16_f32 %0, %1, %2" : "=v"(r) : "v"(lo), "v"(hi));
    return r;
}

// 4 floats -> 4 bf16 (8B store), RNE identical to f2bf.
__device__ __forceinline__ void st_pack4(unsigned short* p, float v0, float v1, float v2, float v3) {
    uint2v u;
    u.x = cvtpk_bf16(v0, v1);
    u.y = cvtpk_bf16(v2, v3);
    *(uint2v*)p = u;
}

// packed fp32 fma: lowers to v_pk_fma_f32 (gfx90a+ packed-FP32; the 157TF
// fp32 peak is only reachable via these). Per-element numerics identical
// to scalar fmaf.
__device__ __forceinline__ floatx2 fma2(floatx2 a, floatx2 b, floatx2 c) {
    return __builtin_elementwise_fma(a, b, c);
}

// All four W1 matrices -> bf16 pre-swizzled MFMA 16x16x32 B-frag order.
// blk = (n>>4)*(H/32) + (k>>5), lane = ((k>>3)&3)*16 + (n&15), j = k&7.
__global__ void convert_all(const float* __restrict__ s0, const float* __restrict__ s1,
                            const float* __restrict__ s2, const float* __restrict__ s3,
                            unsigned short* __restrict__ ws) {
    int idx = blockIdx.x * 256 + threadIdx.x;          // 0 .. 458751
    const float* src; unsigned short* dst; int H, logH, local;
    if (idx < 262144) { src = s0; dst = ws; H = 512; logH = 9; local = idx; }
    else {
        int r = idx - 262144; int m = r >> 16; local = r & 65535;
        H = 256; logH = 8;
        src = (m == 0) ? s1 : (m == 1) ? s2 : s3;
        dst = ws + 262144 + m * 65536;
    }
    int n = local & (H - 1), k = local >> logH;
    int KT = H >> 5;
    int blk = (n >> 4) * KT + (k >> 5);
    int lane = ((k >> 3) & 3) * 16 + (n & 15);
    int j = k & 7;
    dst[(blk * 64 + lane) * 8 + j] = f2bf(src[local]);
}

// R9 = R8 structure (best: 200.5us fused) + packed-FP32 (v_pk_fma_f32) in
// the VALU-dominant regions. R8 budget: VALU-busy ~95us was the largest
// consumer and scalar fmaf runs the fp32 pipe at HALF rate (157TF peak
// requires packed). L0 z-chains 8 scalar -> 4 float2 chains (56->28 fma
// slots/item), jac muls 28->14, d=h-h*h packed; ep j-pairs packed
// (pos 12->8, rpy 8->4 slots/iter). Per-element numerics bit-identical
// (same chain order). Sig exp/rcp stay scalar (trans pipe).
// Sentinels: VGPR <= ~110, FETCH ~5.3MB.
struct PosS {
    float B0[512], B1[512], W2[1536];
    float Q[4][8], Qd[4][8];
    float Sum[32][3];
};
struct RpyS {
    float B0[256], B1[256], W2[512];
    float Q[8][8], Qd[8][8];
    float Sum[64][2];
};

__global__ __launch_bounds__(256, 3)
void fused_mfma(const float* __restrict__ x,
                const float* __restrict__ pW0, const float* __restrict__ pb0,
                const float* __restrict__ pb1,
                const float* __restrict__ pW2, const float* __restrict__ pb2,
                const float* __restrict__ rW0_, const float* __restrict__ rb0_,
                const float* __restrict__ rb1_,
                const float* __restrict__ rW2_, const float* __restrict__ rb2_,
                const float* __restrict__ piW0, const float* __restrict__ pib0,
                const float* __restrict__ pib1,
                const float* __restrict__ piW2, const float* __restrict__ pib2,
                const float* __restrict__ yW0, const float* __restrict__ yb0,
                const float* __restrict__ yb1,
                const float* __restrict__ yW2, const float* __restrict__ yb2,
                const unsigned short* __restrict__ wsBase,
                float* __restrict__ out, int ns)
{
    extern __shared__ unsigned short sA[];      // 34816B: A-tile (16KB) then f32 partials
    __shared__ union { PosS p; RpyS r; } sU;

    const int tid = threadIdx.x;
    const int xcd  = blockIdx.x & 7;
    const int slot = blockIdx.x >> 3;           // 0..1279 within this XCD
    const int o_l  = slot / 5, r5 = slot % 5;
    const int o = xcd + (o_l << 3);             // sample-octet 0..2047

    const size_t JTOT = (size_t)ns * 18, OUTA = (size_t)ns * 81, JANG = (size_t)ns * 87;
    const floatx4 z4 = {0.f, 0.f, 0.f, 0.f};
    const floatx2 z2v = {0.f, 0.f};
    const int w = tid >> 6, lane = tid & 63;
    const int quad = lane >> 4, col = lane & 15;
    const int srcl = lane & 47;
    const int lxk = lane ^ (quad << 1);         // kq-swizzled read index

    if (r5 < 2) {
        // ============ POS: 7 -> 512 -> 512 -> 3, 4 samples (32 rows) ============
        const int m0 = (o * 2 + r5) * 4;
        const unsigned short* wsW1 = wsBase;

        // T14: epilogue params straight into regs (LDS-written post-MFMA)
        const float b1r0 = pb1[tid], b1r1 = pb1[tid + 256];
        float w2r[6];
        #pragma unroll
        for (int t = 0; t < 6; ++t) w2r[t] = pW2[tid + 256 * t];

        for (int i = tid; i < 512; i += 256) sU.p.B0[i] = pb0[i];
        if (tid < 56) {
            int m = tid / 14, c = tid % 14;
            float v = x[(m0 + m) * 14 + c];
            if (c < 7) sU.p.Q[m][c] = v; else sU.p.Qd[m][c - 7] = v;
        }
        __syncthreads();

        const float4* W04 = (const float4*)pW0;

        floatx4 acc[2][8];
        #pragma unroll
        for (int rt = 0; rt < 2; rt++)
            #pragma unroll
            for (int ct = 0; ct < 8; ct++) acc[rt][ct] = z4;

        const short8* bbase = (const short8*)wsW1 + (size_t)(w * 8 * 16) * 64 + lane;
        short8 b0[4], b1[4], b2[4];

#define PLD(B, KT) { \
            B[0] = bbase[((cp4 + 0) * 16 + hh8 + (KT)) * 64]; \
            B[1] = bbase[((cp4 + 1) * 16 + hh8 + (KT)) * 64]; \
            B[2] = bbase[((cp4 + 2) * 16 + hh8 + (KT)) * 64]; \
            B[3] = bbase[((cp4 + 3) * 16 + hh8 + (KT)) * 64]; }
#define PST(B, KT) { \
            const short8 a0 = *(const short8*)&sA[(0 * 8 + (KT)) * 512 + (lxk ^ (KT)) * 8]; \
            const short8 a1 = *(const short8*)&sA[(1 * 8 + (KT)) * 512 + (lxk ^ (KT)) * 8]; \
            acc[0][cp4 + 0] = __builtin_amdgcn_mfma_f32_16x16x32_bf16(a0, B[0], acc[0][cp4 + 0], 0, 0, 0); \
            acc[1][cp4 + 0] = __builtin_amdgcn_mfma_f32_16x16x32_bf16(a1, B[0], acc[1][cp4 + 0], 0, 0, 0); \
            acc[0][cp4 + 1] = __builtin_amdgcn_mfma_f32_16x16x32_bf16(a0, B[1], acc[0][cp4 + 1], 0, 0, 0); \
            acc[1][cp4 + 1] = __builtin_amdgcn_mfma_f32_16x16x32_bf16(a1, B[1], acc[1][cp4 + 1], 0, 0, 0); \
            acc[0][cp4 + 2] = __builtin_amdgcn_mfma_f32_16x16x32_bf16(a0, B[2], acc[0][cp4 + 2], 0, 0, 0); \
            acc[1][cp4 + 2] = __builtin_amdgcn_mfma_f32_16x16x32_bf16(a1, B[2], acc[1][cp4 + 2], 0, 0, 0); \
            acc[0][cp4 + 3] = __builtin_amdgcn_mfma_f32_16x16x32_bf16(a0, B[3], acc[0][cp4 + 3], 0, 0, 0); \
            acc[1][cp4 + 3] = __builtin_amdgcn_mfma_f32_16x16x32_bf16(a1, B[3], acc[1][cp4 + 3], 0, 0, 0); }

        #pragma unroll
        for (int hh = 0; hh < 2; ++hh) {
            const int hh8 = hh * 8;
            // T14: cp0's first fragment set, issued before L0 (independent of sA)
            b0[0] = bbase[(0 * 16 + hh8) * 64];
            b0[1] = bbase[(1 * 16 + hh8) * 64];
            b0[2] = bbase[(2 * 16 + hh8) * 64];
            b0[3] = bbase[(3 * 16 + hh8) * 64];
            // ---- layer 0, K-half hh: 256 threads = 4 samples x 32 k8 x 2 jj-halves ----
            {
                const int jh = tid & 1, item = tid >> 1;
                const int s = item >> 5, k8l = item & 31, k8 = (hh << 5) | k8l;
                float q[7]; floatx2 w0a[7], w0b[7];
                #pragma unroll
                for (int i = 0; i < 7; i++) {
                    q[i] = sU.p.Q[s][i];
                    float4 a = W04[i * 128 + k8 * 2 + jh];
                    w0a[i] = (floatx2){a.x, a.y};
                    w0b[i] = (floatx2){a.z, a.w};
                }
                const float* bb = &sU.p.B0[k8 * 8 + jh * 4];
                floatx2 za = {bb[0], bb[1]}, zb = {bb[2], bb[3]};
                #pragma unroll
                for (int i = 0; i < 7; i++) {
                    floatx2 qs = {q[i], q[i]};
                    za = fma2(qs, w0a[i], za);
                    zb = fma2(qs, w0b[i], zb);
                }
                floatx2 ha = {sig(za[0]), sig(za[1])};
                floatx2 hb = {sig(zb[0]), sig(zb[1])};
                floatx2 da = ha - ha * ha;
                floatx2 db = hb - hb * hb;
                const int ktl = k8l >> 2, kq = k8l & 3;
                const int kxr = (kq << 4) ^ (kq << 1) ^ ktl;   // slot = kxr ^ (rr&15)
                const int rr0 = s * 8;
                st_pack4(&sA[((rr0 >> 4) * 8 + ktl) * 512 + (kxr ^ (rr0 & 15)) * 8 + jh * 4],
                         ha[0], ha[1], hb[0], hb[1]);
                #pragma unroll
                for (int i = 0; i < 7; i++) {
                    const int rr = rr0 + 1 + i;
                    floatx2 ta = da * w0a[i], tb = db * w0b[i];
                    st_pack4(&sA[((rr >> 4) * 8 + ktl) * 512 + (kxr ^ (rr & 15)) * 8 + jh * 4],
                             ta[0], ta[1], tb[0], tb[1]);
                }
            }
            __syncthreads();

            // ---- layer 1 MFMA over this K-half, 2 ct-passes of 4, 3-buf rotation ----
            #pragma unroll
            for (int cp = 0; cp < 2; ++cp) {
                const int cp4 = cp * 4;
                if (cp) PLD(b0, 0);
                PLD(b1, 1); PLD(b2, 2);
                __builtin_amdgcn_s_setprio(1);
                PST(b0, 0); PLD(b0, 3);
                PST(b1, 1); PLD(b1, 4);
                PST(b2, 2); PLD(b2, 5);
                PST(b0, 3); PLD(b0, 6);
                PST(b1, 4); PLD(b1, 7);
                PST(b2, 5);
                PST(b0, 6);
                PST(b1, 7);
                __builtin_amdgcn_s_setprio(0);
            }
            if (hh == 0) __syncthreads();   // drain reads before half-1 overwrites sA
        }
#undef PLD
#undef PST

        // T14: write epilogue params to LDS; barrier also closes A-tile reads
        sU.p.B1[tid] = b1r0; sU.p.B1[tid + 256] = b1r1;
        #pragma unroll
        for (int t = 0; t < 6; ++t) sU.p.W2[tid + 256 * t] = w2r[t];
        __syncthreads();

        floatx2 epv[2][4]; float eps[2][4];
        #pragma unroll
        for (int a = 0; a < 2; a++) for (int b = 0; b < 4; b++) { epv[a][b] = z2v; eps[a][b] = 0.f; }

        #pragma unroll
        for (int ct = 0; ct < 8; ++ct) {
            const int n = w * 128 + ct * 16 + col;
            const float b1n = sU.p.B1[n];
            const floatx2 w201 = {sU.p.W2[n * 3], sU.p.W2[n * 3 + 1]};
            const float w22 = sU.p.W2[n * 3 + 2];
            #pragma unroll
            for (int rt = 0; rt < 2; ++rt) {
                float z2c = __shfl(acc[rt][ct][0], srcl);
                float h2 = sig(z2c + b1n);
                float d2 = h2 - h2 * h2;
                #pragma unroll
                for (int r = 0; r < 4; ++r) {
                    float gg = ((quad & 1) == 0 && r == 0) ? h2 : d2 * acc[rt][ct][r];
                    epv[rt][r] = fma2((floatx2){gg, gg}, w201, epv[rt][r]);
                    eps[rt][r] = fmaf(gg, w22, eps[rt][r]);
                }
            }
        }

        // LDS-transpose reduce: partials [w][row][j][17] f32 in sA (A-tile dead)
        {
            float* pl = (float*)sA;
            #pragma unroll
            for (int rt = 0; rt < 2; ++rt)
                #pragma unroll
                for (int r = 0; r < 4; ++r) {
                    int row = rt * 16 + quad * 4 + r;
                    int base = ((w * 32 + row) * 3) * 17 + col;
                    pl[base]      = epv[rt][r][0];
                    pl[base + 17] = epv[rt][r][1];
                    pl[base + 34] = eps[rt][r];
                }
        }
        __syncthreads();

        if (tid < 96) {
            const float* pl = (const float*)sA;
            int row = tid / 3, j = tid % 3;
            float v = 0.f;
            #pragma unroll
            for (int ww = 0; ww < 4; ++ww) {
                const float* q = &pl[((ww * 32 + row) * 3 + j) * 17];
                #pragma unroll
                for (int c = 0; c < 16; ++c) v += q[c];
            }
            int s = row >> 3, i = row & 7;
            size_t M = m0 + s;
            if (i == 0) { v += pb2[j]; out[M * 18 + j] = v; out[OUTA + M * 6 + j] = v; }
            else        { out[JTOT + M * 63 + j * 7 + (i - 1)] = v;
                          out[JANG + M * 42 + j * 7 + (i - 1)] = v; }
            sU.p.Sum[row][j] = v;
        }
        __syncthreads();
        if (tid < 12) {
            int s = tid / 3, j = tid % 3;
            float vel = 0.f;
            #pragma unroll
            for (int i = 0; i < 7; i++) vel = fmaf(sU.p.Sum[s * 8 + 1 + i][j], sU.p.Qd[s][i], vel);
            out[(size_t)(m0 + s) * 18 + 9 + j] = vel;
        }
    } else {
        // ============ RPY: 7 -> 256 -> 256 -> 2, 8 samples (64 rows) ============
        const int h = r5 - 2;
        const int m0 = o * 8;
        const float* W0 = (h == 0) ? rW0_ : (h == 1) ? piW0 : yW0;
        const float* b0p = (h == 0) ? rb0_ : (h == 1) ? pib0 : yb0;
        const float* b1p = (h == 0) ? rb1_ : (h == 1) ? pib1 : yb1;
        const float* W2 = (h == 0) ? rW2_ : (h == 1) ? piW2 : yW2;
        const float* b2p = (h == 0) ? rb2_ : (h == 1) ? pib2 : yb2;
        const unsigned short* wsW1 = wsBase + 262144 + h * 65536;

        // T14: epilogue params straight into regs (LDS-written post-MFMA)
        const float b1r0 = b1p[tid];
        const float w2r0 = W2[tid], w2r1 = W2[tid + 256];

        if (tid < 256) sU.r.B0[tid] = b0p[tid];
        if (tid < 112) {
            int m = tid / 14, c = tid % 14;
            float v = x[(m0 + m) * 14 + c];
            if (c < 7) sU.r.Q[m][c] = v; else sU.r.Qd[m][c - 7] = v;
        }
        __syncthreads();

        const float4* W04 = (const float4*)W0;

        floatx4 acc[4][4];
        #pragma unroll
        for (int rt = 0; rt < 4; rt++)
            #pragma unroll
            for (int ct = 0; ct < 4; ct++) acc[rt][ct] = z4;

        const short8* bbase = (const short8*)wsW1 + (size_t)(w * 4 * 8) * 64 + lane;
        short8 b0[2], b1[2], b2[2];

#define RLD(B, KT) { \
            B[0] = bbase[((cp2 + 0) * 8 + hh4 + (KT)) * 64]; \
            B[1] = bbase[((cp2 + 1) * 8 + hh4 + (KT)) * 64]; }
#define RST(B, KT) { \
            const int sw_ = hh4 + (KT); \
            const short8 a0 = *(const short8*)&sA[(0 * 4 + (KT)) * 512 + (lxk ^ sw_) * 8]; \
            const short8 a1 = *(const short8*)&sA[(1 * 4 + (KT)) * 512 + (lxk ^ sw_) * 8]; \
            const short8 a2 = *(const short8*)&sA[(2 * 4 + (KT)) * 512 + (lxk ^ sw_) * 8]; \
            const short8 a3 = *(const short8*)&sA[(3 * 4 + (KT)) * 512 + (lxk ^ sw_) * 8]; \
            acc[0][cp2 + 0] = __builtin_amdgcn_mfma_f32_16x16x32_bf16(a0, B[0], acc[0][cp2 + 0], 0, 0, 0); \
            acc[1][cp2 + 0] = __builtin_amdgcn_mfma_f32_16x16x32_bf16(a1, B[0], acc[1][cp2 + 0], 0, 0, 0); \
            acc[2][cp2 + 0] = __builtin_amdgcn_mfma_f32_16x16x32_bf16(a2, B[0], acc[2][cp2 + 0], 0, 0, 0); \
            acc[3][cp2 + 0] = __builtin_amdgcn_mfma_f32_16x16x32_bf16(a3, B[0], acc[3][cp2 + 0], 0, 0, 0); \
            acc[0][cp2 + 1] = __builtin_amdgcn_mfma_f32_16x16x32_bf16(a0, B[1], acc[0][cp2 + 1], 0, 0, 0); \
            acc[1][cp2 + 1] = __builtin_amdgcn_mfma_f32_16x16x32_bf16(a1, B[1], acc[1][cp2 + 1], 0, 0, 0); \
            acc[2][cp2 + 1] = __builtin_amdgcn_mfma_f32_16x16x32_bf16(a2, B[1], acc[2][cp2 + 1], 0, 0, 0); \
            acc[3][cp2 + 1] = __builtin_amdgcn_mfma_f32_16x16x32_bf16(a3, B[1], acc[3][cp2 + 1], 0, 0, 0); }

        #pragma unroll
        for (int hh = 0; hh < 2; ++hh) {
            const int hh4 = hh * 4;
            // T14: cp0's first fragment set, issued before L0 (independent of sA)
            b0[0] = bbase[(0 * 8 + hh4) * 64];
            b0[1] = bbase[(1 * 8 + hh4) * 64];
            // ---- layer 0, K-half hh: 256 threads = 8 samples x 16 k8 x 2 jj-halves ----
            {
                const int jh = tid & 1, item = tid >> 1;
                const int s = item >> 4, k8l = item & 15, k8 = (hh << 4) | k8l;
                float q[7]; floatx2 w0a[7], w0b[7];
                #pragma unroll
                for (int i = 0; i < 7; i++) {
                    q[i] = sU.r.Q[s][i];
                    float4 a = W04[i * 64 + k8 * 2 + jh];
                    w0a[i] = (floatx2){a.x, a.y};
                    w0b[i] = (floatx2){a.z, a.w};
                }
                const float* bb = &sU.r.B0[k8 * 8 + jh * 4];
                floatx2 za = {bb[0], bb[1]}, zb = {bb[2], bb[3]};
                #pragma unroll
                for (int i = 0; i < 7; i++) {
                    floatx2 qs = {q[i], q[i]};
                    za = fma2(qs, w0a[i], za);
                    zb = fma2(qs, w0b[i], zb);
                }
                floatx2 ha = {sig(za[0]), sig(za[1])};
                floatx2 hb = {sig(zb[0]), sig(zb[1])};
                floatx2 da = ha - ha * ha;
                floatx2 db = hb - hb * hb;
                const int ktl = k8l >> 2, kq = k8l & 3;
                const int sw = (hh << 2) | ktl;              // global kt & 7
                const int kxr = (kq << 4) ^ (kq << 1) ^ sw;  // slot = kxr ^ (rr&15)
                const int rr0 = s * 8;
                st_pack4(&sA[((rr0 >> 4) * 4 + ktl) * 512 + (kxr ^ (rr0 & 15)) * 8 + jh * 4],
                         ha[0], ha[1], hb[0], hb[1]);
                #pragma unroll
                for (int i = 0; i < 7; i++) {
                    const int rr = rr0 + 1 + i;
                    floatx2 ta = da * w0a[i], tb = db * w0b[i];
                    st_pack4(&sA[((rr >> 4) * 4 + ktl) * 512 + (kxr ^ (rr & 15)) * 8 + jh * 4],
                             ta[0], ta[1], tb[0], tb[1]);
                }
            }
            __syncthreads();

            // ---- layer 1 MFMA over this K-half, 2 ct-passes of 2, 3-buf rotation ----
            #pragma unroll
            for (int cp = 0; cp < 2; ++cp) {
                const int cp2 = cp * 2;
                if (cp) RLD(b0, 0);
                RLD(b1, 1); RLD(b2, 2);
                __builtin_amdgcn_s_setprio(1);
                RST(b0, 0); RLD(b0, 3);
                RST(b1, 1);
                RST(b2, 2);
                RST(b0, 3);
                __builtin_amdgcn_s_setprio(0);
            }
            if (hh == 0) __syncthreads();   // drain reads before half-1 overwrites sA
        }
#undef RLD
#undef RST

        // T14: write epilogue params to LDS; barrier also closes A-tile reads
        sU.r.B1[tid] = b1r0;
        sU.r.W2[tid] = w2r0; sU.r.W2[tid + 256] = w2r1;
        __syncthreads();

        floatx2 epv[4][4];
        #pragma unroll
        for (int a = 0; a < 4; a++) for (int b = 0; b < 4; b++) epv[a][b] = z2v;

        #pragma unroll
        for (int ct = 0; ct < 4; ++ct) {
            const int n = w * 64 + ct * 16 + col;
            const float b1n = sU.r.B1[n];
            const floatx2 w201 = {sU.r.W2[n * 2], sU.r.W2[n * 2 + 1]};
            #pragma unroll
            for (int rt = 0; rt < 4; ++rt) {
                float z2c = __shfl(acc[rt][ct][0], srcl);
                float h2 = sig(z2c + b1n);
                float d2 = h2 - h2 * h2;
                #pragma unroll
                for (int r = 0; r < 4; ++r) {
                    float gg = ((quad & 1) == 0 && r == 0) ? h2 : d2 * acc[rt][ct][r];
                    epv[rt][r] = fma2((floatx2){gg, gg}, w201, epv[rt][r]);
                }
            }
        }

        // LDS-transpose reduce: partials [w][row][j][17] f32 in sA (A-tile dead)
        {
            float* pl = (float*)sA;
            #pragma unroll
            for (int rt = 0; rt < 4; ++rt)
                #pragma unroll
                for (int r = 0; r < 4; ++r) {
                    int row = rt * 16 + quad * 4 + r;
                    int base = ((w * 64 + row) * 2) * 17 + col;
                    pl[base]      = epv[rt][r][0];
                    pl[base + 17] = epv[rt][r][1];
                }
        }
        __syncthreads();

        if (tid < 128) {
            const float* pl = (const float*)sA;
            int row = tid >> 1, j = tid & 1;
            float v = 0.f;
            #pragma unroll
            for (int ww = 0; ww < 4; ++ww) {
                const float* q = &pl[((ww * 64 + row) * 2 + j) * 17];
                #pragma unroll
                for (int c = 0; c < 16; ++c) v += q[c];
            }
            if ((row & 7) == 0) v += b2p[j];
            sU.r.Sum[row][j] = v;
        }
        __syncthreads();

        if (tid < 8) {
            int s = tid;
            size_t M = m0 + s;
            float y0 = sU.r.Sum[s * 8][0], y1 = sU.r.Sum[s * 8][1];
            float sv = sinf(y0), cv = cosf(y1);
            out[M * 18 + 3 + h] = sv;
            out[M * 18 + 6 + h] = cv;
            out[OUTA + M * 6 + 3 + h] = atan2f(sv, cv);
            float f0 = cosf(y0), f1 = -sinf(y1);
            float inv = 1.0f / fmaf(sv, sv, cv * cv);
            float v0 = 0.f, v1 = 0.f;
            #pragma unroll
            for (int i = 0; i < 7; i++) {
                float r0 = f0 * sU.r.Sum[s * 8 + 1 + i][0];
                float r1 = f1 * sU.r.Sum[s * 8 + 1 + i][1];
                out[JTOT + M * 63 + (3 + h) * 7 + i] = r0;
                out[JTOT + M * 63 + (6 + h) * 7 + i] = r1;
                out[JANG + M * 42 + (3 + h) * 7 + i] = (cv * r0 - sv * r1) * inv;
                v0 = fmaf(r0, sU.r.Qd[s][i], v0);
                v1 = fmaf(r1, sU.r.Qd[s][i], v1);
            }
            out[M * 18 + 12 + h] = v0;
            out[M * 18 + 15 + h] = v1;
        }
    }
}

extern "C" void kernel_launch(void* const* d_in, const int* in_sizes, int n_in,
                              void* d_out, int out_size, void* d_ws, size_t ws_size,
                              hipStream_t stream) {
    (void)n_in; (void)out_size; (void)ws_size;
    const float* x = (const float*)d_in[0];
    float* out = (float*)d_out;
    unsigned short* ws = (unsigned short*)d_ws;
    const int ns = in_sizes[0] / 14;

    convert_all<<<dim3(1792), 256, 0, stream>>>(
        (const float*)d_in[3], (const float*)d_in[9],
        (const float*)d_in[15], (const float*)d_in[21], ws);

    // 10240 blocks (2048 octets x 5 roles); 34816B dynamic LDS
    fused_mfma<<<dim3((ns / 8) * 5), 256, 34816, stream>>>(
        x,
        (const float*)d_in[1],  (const float*)d_in[2],  (const float*)d_in[4],
        (const float*)d_in[5],  (const float*)d_in[6],
        (const float*)d_in[7],  (const float*)d_in[8],  (const float*)d_in[10],
        (const float*)d_in[11], (const float*)d_in[12],
        (const float*)d_in[13], (const float*)d_in[14], (const float*)d_in[16],
        (const float*)d_in[17], (const float*)d_in[18],
        (const float*)d_in[19], (const float*)d_in[20], (const float*)d_in[22],
        (const float*)d_in[23], (const float*)d_in[24],
        ws, out, ns);
}